// Round 13
// baseline (412.973 us; speedup 1.0000x reference)
//
#include <hip/hip_runtime.h>
#include <hip/hip_bf16.h>
#include <stdint.h>

typedef float  f32x4 __attribute__((ext_vector_type(4)));
typedef short  s16x8 __attribute__((ext_vector_type(8)));
typedef unsigned short u16x8 __attribute__((ext_vector_type(8)));
typedef unsigned short ushort_t;

__device__ __forceinline__ short f2bf(float f) {
  union { float f; unsigned u; } x; x.f = f;
  unsigned r = x.u + 0x7fffu + ((x.u >> 16) & 1u);
  return (short)(r >> 16);
}
__device__ __forceinline__ float bf2f(unsigned short u) {
  union { unsigned u; float f; } x; x.u = ((unsigned)u) << 16; return x.f;
}

// ---------------- merged weight pack (8 regions) + time embedding (last block)
__device__ __forceinline__ void pack_one(const float* W, int cols, int local, short* dst) {
  int NT = cols / 16;
  int j = local & 7, l = (local >> 3) & 63;
  int nt = (local >> 9) % NT;
  int kt = (local >> 9) / NT;
  int k = kt * 32 + ((l >> 4) * 8) + j;
  int ncol = nt * 16 + (l & 15);
  dst[local] = f2bf(W[(size_t)k * cols + ncol]);
}
__global__ void k_pack_all(const float* __restrict__ w0, const float* __restrict__ w1,
                           const float* __restrict__ w2, const float* __restrict__ w3,
                           const float* __restrict__ w4, const float* __restrict__ w5,
                           const float* __restrict__ w6, const float* __restrict__ w7,
                           short* __restrict__ out,
                           const int* __restrict__ t, const float* __restrict__ tw1,
                           const float* __restrict__ tb1, const float* __restrict__ tw2,
                           const float* __restrict__ tb2, float* __restrict__ temb) {
  if (blockIdx.x == 448) {            // time embedding
    __shared__ float h[32];
    int j = threadIdx.x;
    float tin = (float)t[0] / 1000.0f;
    if (j < 32) h[j] = fmaxf(tin * tw1[j] + tb1[j], 0.f);
    __syncthreads();
    if (j < 32) {
      float acc = tb2[j];
      for (int k = 0; k < 32; ++k) acc += h[k] * tw2[k * 32 + j];
      temb[j] = acc;
    }
    return;
  }
  int i = blockIdx.x * 256 + threadIdx.x;
  if (i >= 114688) return;
  if (i < 98304) {
    int r = i >> 14, local = i & 16383;
    const float* W = r == 0 ? w0 : r == 1 ? w1 : r == 2 ? w2 : r == 3 ? w3 : r == 4 ? w4 : w5;
    pack_one(W, 128, local, out + r * 16384);
  } else {
    int j = i - 98304;
    int r = j >> 13, local = j & 8191;
    pack_one(r ? w7 : w6, 64, local, out + 98304 + r * 8192);
  }
}

// ---------------- x_input = [x_t | cond | t_embed] -> bf16
__global__ void k_build_xin(const float* __restrict__ xt, const float* __restrict__ cond,
                            const float* __restrict__ temb, ushort_t* __restrict__ X, int n) {
  int i = blockIdx.x * 256 + threadIdx.x;   // over n*16, 8 cols each
  if (i >= n * 16) return;
  int node = i >> 4, c8 = i & 15;
  float4 a, b;
  if (c8 < 8)       { const float* p = &xt[(size_t)node * 64 + c8 * 8];
                      a = *(const float4*)p; b = *(const float4*)(p + 4); }
  else if (c8 < 12) { const float* p = &cond[(c8 - 8) * 8];
                      a = *(const float4*)p; b = *(const float4*)(p + 4); }
  else              { const float* p = &temb[(c8 - 12) * 8];
                      a = *(const float4*)p; b = *(const float4*)(p + 4); }
  u16x8 o;
  o[0]=f2bf(a.x); o[1]=f2bf(a.y); o[2]=f2bf(a.z); o[3]=f2bf(a.w);
  o[4]=f2bf(b.x); o[5]=f2bf(b.y); o[6]=f2bf(b.z); o[7]=f2bf(b.w);
  *(u16x8*)&X[(size_t)node * 128 + c8 * 8] = o;
}

// ---------------- CSR build ----------------
__global__ void k_deg_init(int* __restrict__ deg, int n) {
  int i = blockIdx.x * 256 + threadIdx.x;
  if (i < n) deg[i] = 1;
}
__global__ void k_deg_count(const int* __restrict__ edst, int E, int* __restrict__ deg) {
  int e = blockIdx.x * 256 + threadIdx.x;
  if (e < E) atomicAdd(&deg[edst[e]], 1);
}
__global__ void k_scan1(const int* __restrict__ deg, int* __restrict__ tmp,
                        int* __restrict__ bsum, int n) {
  __shared__ int sh[256];
  int i = blockIdx.x * 256 + threadIdx.x;
  int v = (i < n) ? deg[i] : 0;
  sh[threadIdx.x] = v; __syncthreads();
  for (int off = 1; off < 256; off <<= 1) {
    int t = (threadIdx.x >= off) ? sh[threadIdx.x - off] : 0;
    __syncthreads();
    sh[threadIdx.x] += t;
    __syncthreads();
  }
  if (i < n) tmp[i] = sh[threadIdx.x];
  if (threadIdx.x == 255) bsum[blockIdx.x] = sh[255];
}
__global__ void k_scan2(int* __restrict__ bsum, int nb) {
  __shared__ int sh[256];
  int t = threadIdx.x;
  int v = (t < nb) ? bsum[t] : 0;
  sh[t] = v; __syncthreads();
  for (int off = 1; off < 256; off <<= 1) {
    int u = (t >= off) ? sh[t - off] : 0;
    __syncthreads();
    sh[t] += u;
    __syncthreads();
  }
  if (t < nb) bsum[t] = sh[t] - v;
}
// cursor padded: one counter per 128B line (index i*32)
__global__ void k_scan3(const int* __restrict__ deg, const int* __restrict__ tmp,
                        const int* __restrict__ bsum, int* __restrict__ row,
                        int* __restrict__ cursor, int n) {
  int i = blockIdx.x * 256 + threadIdx.x;
  if (i < n) {
    int incl = tmp[i] + bsum[i >> 8];
    row[i + 1] = incl;
    cursor[(size_t)i * 32] = incl - deg[i];
    if (i == 0) row[0] = 0;
  }
}
// scatter: ONLY perm[slot] = e (one random 4B store per edge)
__global__ void k_scatter(const int* __restrict__ ei, int E, int nE,
                          int* __restrict__ cursor, int* __restrict__ perm) {
  int e = blockIdx.x * 256 + threadIdx.x;
  if (e >= nE) return;
  int d = (e < E) ? ei[E + e] : e - E;
  int slot = atomicAdd(&cursor[(size_t)d * 32], 1);
  perm[slot] = e;
}
// fill: sequential in CSR slot order; all writes sequential.
// Also computes layer-1 aux (dist + coord-MLP * edge_vec).
__global__ __launch_bounds__(256)
void k_fill(const int* __restrict__ perm, const int* __restrict__ ei, int E, int nE,
            const float* __restrict__ pos,
            const float* __restrict__ cw1, const float* __restrict__ cb1,
            const float* __restrict__ cw2, const float* __restrict__ cb2,
            int* __restrict__ csr_src, int* __restrict__ csr_dst,
            int* __restrict__ csr_eid, float4* __restrict__ aux) {
  int k = blockIdx.x * 256 + threadIdx.x;
  if (k >= nE) return;
  int e = perm[k];
  int s, d, id;
  if (e < E) { s = ei[e]; d = ei[E + e]; id = e; }
  else       { s = d = e - E; id = -1; }
  csr_src[k] = s;
  csr_dst[k] = d;
  csr_eid[k] = id;
  float dx = pos[s*3+0] - pos[d*3+0];
  float dy = pos[s*3+1] - pos[d*3+1];
  float dz = pos[s*3+2] - pos[d*3+2];
  float dist = sqrtf(dx*dx + dy*dy + dz*dz + 1e-8f);
  float h = cb2[0];
  #pragma unroll 4
  for (int j = 0; j < 128; ++j)
    h += fmaxf(fmaf(dist, cw1[j], cb1[j]), 0.f) * cw2[j];
  float4 o; o.x = dist; o.y = h * dx; o.z = h * dy; o.w = h * dz;
  aux[k] = o;
}

// ---------------- single node GEMM: out = bf16A[n][128] @ Wp + degf*bias + residb
template<int COLS, bool OUTBF16>
__global__ __launch_bounds__(256)
void k_mgemm(const ushort_t* __restrict__ A, const short* __restrict__ Wp,
             const float* __restrict__ bias, const ushort_t* __restrict__ resid,
             const float* __restrict__ degf, void* __restrict__ out,
             float* __restrict__ out64, int n) {
  const int NT = COLS / 16;
  __shared__ short BL[128 * COLS];
  for (int i = threadIdx.x; i < 128 * COLS / 8; i += 256)
    ((int4*)BL)[i] = ((const int4*)Wp)[i];
  __syncthreads();
  int t = threadIdx.x, wid = t >> 6, lane = t & 63;
  int cg = lane >> 4;
  float bb[NT];
  #pragma unroll
  for (int nt = 0; nt < NT; ++nt)
    bb[nt] = bias ? bias[nt * 16 + (lane & 15)] : 0.f;
  int ntiles = (n + 15) >> 4;
  for (int tile = blockIdx.x * 4 + wid; tile < ntiles; tile += gridDim.x * 4) {
    int r0 = tile << 4;
    int arow = r0 + (lane & 15);
    int crow = arow < n ? arow : 0;
    const ushort_t* Ar = A + (size_t)crow * 128;
    s16x8 Af[4];
    #pragma unroll
    for (int kt = 0; kt < 4; ++kt)
      Af[kt] = *(const s16x8*)(Ar + kt * 32 + cg * 8);
    float dsc[4];
    #pragma unroll
    for (int reg = 0; reg < 4; ++reg) {
      int rr = r0 + cg * 4 + reg;
      dsc[reg] = degf ? degf[rr < n ? rr : 0] : 1.f;
    }
    #pragma unroll
    for (int nt = 0; nt < NT; ++nt) {
      f32x4 acc = {0.f, 0.f, 0.f, 0.f};
      #pragma unroll
      for (int kt = 0; kt < 4; ++kt) {
        s16x8 b = *(const s16x8*)&BL[((kt * NT + nt) * 64 + lane) * 8];
        acc = __builtin_amdgcn_mfma_f32_16x16x32_bf16(Af[kt], b, acc, 0, 0, 0);
      }
      int ncol = nt * 16 + (lane & 15);
      #pragma unroll
      for (int reg = 0; reg < 4; ++reg) {
        int rr = r0 + cg * 4 + reg;
        if (rr < n) {
          float v = acc[reg] + dsc[reg] * bb[nt];
          if (resid) v += bf2f(resid[(size_t)rr * COLS + ncol]);
          if (OUTBF16) ((ushort_t*)out)[(size_t)rr * COLS + ncol] = (ushort_t)f2bf(v);
          else         ((float*)out)[(size_t)rr * COLS + ncol] = v;
          if (out64 && ncol < 64) out64[(size_t)rr * 64 + ncol] = v;
        }
      }
    }
  }
}

// ---------------- dual node GEMM (256 threads): same bf16 A, two packed weights
template<int COLS>
__global__ __launch_bounds__(256)
void k_mgemm_dual(const ushort_t* __restrict__ A, const short* __restrict__ Wp,
                  const float* __restrict__ bias1,
                  ushort_t* __restrict__ out1, ushort_t* __restrict__ out2, int n) {
  const int NT = COLS / 16;
  __shared__ short BL[2 * 128 * COLS];
  for (int i = threadIdx.x; i < 2 * 128 * COLS / 8; i += 256)
    ((int4*)BL)[i] = ((const int4*)Wp)[i];
  __syncthreads();
  int t = threadIdx.x, wid = t >> 6, lane = t & 63;
  int cg = lane >> 4;
  float bb[NT];
  #pragma unroll
  for (int nt = 0; nt < NT; ++nt)
    bb[nt] = bias1 ? bias1[nt * 16 + (lane & 15)] : 0.f;
  int ntiles = (n + 15) >> 4;
  for (int tile = blockIdx.x * 4 + wid; tile < ntiles; tile += gridDim.x * 4) {
    int r0 = tile << 4;
    int arow = r0 + (lane & 15);
    int crow = arow < n ? arow : 0;
    const ushort_t* Ar = A + (size_t)crow * 128;
    s16x8 Af[4];
    #pragma unroll
    for (int kt = 0; kt < 4; ++kt)
      Af[kt] = *(const s16x8*)(Ar + kt * 32 + cg * 8);
    #pragma unroll
    for (int w = 0; w < 2; ++w) {
      ushort_t* outp = w ? out2 : out1;
      #pragma unroll
      for (int nt = 0; nt < NT; ++nt) {
        f32x4 acc = {0.f, 0.f, 0.f, 0.f};
        #pragma unroll
        for (int kt = 0; kt < 4; ++kt) {
          s16x8 b = *(const s16x8*)&BL[(w * 128 * COLS / 8 + (kt * NT + nt) * 64 + lane) * 8];
          acc = __builtin_amdgcn_mfma_f32_16x16x32_bf16(Af[kt], b, acc, 0, 0, 0);
        }
        int ncol = nt * 16 + (lane & 15);
        float badd = w ? 0.f : bb[nt];
        #pragma unroll
        for (int reg = 0; reg < 4; ++reg) {
          int rr = r0 + cg * 4 + reg;
          if (rr < n)
            outp[(size_t)rr * COLS + ncol] = (ushort_t)f2bf(acc[reg] + badd);
        }
      }
    }
  }
}

// ---------------- per-dst aggregation: one wave per node, TWO 32-lane half-streams.
// L1: per-edge data from aux4 (dist + premultiplied coord vec).
// L2: dist computed inline from pos (wave-uniform s -> broadcast 12B load, L2-hot).
template<bool L1>
__global__ __launch_bounds__(256)
void k_aggregate(const int* __restrict__ row, const int* __restrict__ csr_src,
                 const float4* __restrict__ aux4,
                 const ushort_t* __restrict__ Pb, const ushort_t* __restrict__ Qb,
                 const float* __restrict__ w1r,
                 const float* __restrict__ posin, float* __restrict__ posout,
                 float* __restrict__ degf, ushort_t* __restrict__ Sb, int n) {
  int gw = (blockIdx.x * 256 + threadIdx.x) >> 6;
  if (gw >= n) return;
  int lane = threadIdx.x & 63;
  int half = lane >> 5, sub = lane & 31;
  int r0 = row[gw], r1 = row[gw + 1];
  int r1m1 = r1 - 1;                       // deg >= 1 (self loop)

  ushort4 pu = *(const ushort4*)&Pb[(size_t)gw * 128 + (sub << 2)];
  float p0 = bf2f(pu.x), p1 = bf2f(pu.y), p2 = bf2f(pu.z), p3 = bf2f(pu.w);
  float4 wv = *(const float4*)&w1r[sub << 2];
  float a0 = 0.f, a1 = 0.f, a2 = 0.f, a3 = 0.f, pacc = 0.f;
  float pix = 0.f, piy = 0.f, piz = 0.f;
  if (!L1) { pix = posin[gw*3+0]; piy = posin[gw*3+1]; piz = posin[gw*3+2]; }

  int k0 = r0 + half;
  bool any = k0 < r1;
  int kA = k0 < r1m1 ? k0 : r1m1;
  int kB = k0 + 2 < r1m1 ? k0 + 2 : r1m1;
  int sA = csr_src[kA];
  int sB = csr_src[kB];
  ushort4 qA = *(const ushort4*)&Qb[(size_t)sA * 128 + (sub << 2)];
  float4 axA, axB;
  if (L1) axA = aux4[kA];
  else  { axA.x = posin[sA*3+0]; axA.y = posin[sA*3+1]; axA.z = posin[sA*3+2]; axA.w = 0.f; }

  for (int k = k0; k + 2 < r1; k += 2) {
    int kn4 = k + 4 < r1m1 ? k + 4 : r1m1;
    int sC = csr_src[kn4];
    ushort4 qB = *(const ushort4*)&Qb[(size_t)sB * 128 + (sub << 2)];
    if (L1) axB = aux4[k + 2];
    else  { axB.x = posin[sB*3+0]; axB.y = posin[sB*3+1]; axB.z = posin[sB*3+2]; axB.w = 0.f; }
    float dist;
    if (L1) dist = axA.x;
    else {
      float dx = axA.x - pix, dy = axA.y - piy, dz = axA.z - piz;
      dist = sqrtf(dx*dx + dy*dy + dz*dz + 1e-8f);
    }
    a0 += fmaxf(fmaf(dist, wv.x, p0 + bf2f(qA.x)), 0.f);
    a1 += fmaxf(fmaf(dist, wv.y, p1 + bf2f(qA.y)), 0.f);
    a2 += fmaxf(fmaf(dist, wv.z, p2 + bf2f(qA.z)), 0.f);
    a3 += fmaxf(fmaf(dist, wv.w, p3 + bf2f(qA.w)), 0.f);
    if (L1 && sub < 3) pacc += (sub == 0) ? axA.y : (sub == 1) ? axA.z : axA.w;
    qA = qB; axA = axB; sB = sC;
  }
  if (any) {
    float dist;
    if (L1) dist = axA.x;
    else {
      float dx = axA.x - pix, dy = axA.y - piy, dz = axA.z - piz;
      dist = sqrtf(dx*dx + dy*dy + dz*dz + 1e-8f);
    }
    a0 += fmaxf(fmaf(dist, wv.x, p0 + bf2f(qA.x)), 0.f);
    a1 += fmaxf(fmaf(dist, wv.y, p1 + bf2f(qA.y)), 0.f);
    a2 += fmaxf(fmaf(dist, wv.z, p2 + bf2f(qA.z)), 0.f);
    a3 += fmaxf(fmaf(dist, wv.w, p3 + bf2f(qA.w)), 0.f);
    if (L1 && sub < 3) pacc += (sub == 0) ? axA.y : (sub == 1) ? axA.z : axA.w;
  }

  // merge the two halves
  a0 += __shfl_xor(a0, 32, 64);
  a1 += __shfl_xor(a1, 32, 64);
  a2 += __shfl_xor(a2, 32, 64);
  a3 += __shfl_xor(a3, 32, 64);
  if (L1) pacc += __shfl_xor(pacc, 32, 64);

  if (half == 0) {
    ushort4 o;
    o.x = (ushort_t)f2bf(a0); o.y = (ushort_t)f2bf(a1);
    o.z = (ushort_t)f2bf(a2); o.w = (ushort_t)f2bf(a3);
    *(ushort4*)&Sb[(size_t)gw * 128 + (sub << 2)] = o;
  }
  if (L1) {
    if (lane < 3) posout[gw * 3 + lane] = posin[gw * 3 + lane] + pacc;
    if (lane == 0) degf[gw] = (float)(r1 - r0);
  }
}

// ---------------- bond predictor in CSR(dst) order: V[d] L2-hot, write out[eid]
__global__ __launch_bounds__(256)
void k_bond(const int* __restrict__ csr_src, const int* __restrict__ csr_dst,
            const int* __restrict__ csr_eid, int nE,
            const ushort_t* __restrict__ U, const ushort_t* __restrict__ V,
            const float* __restrict__ w2, const float* __restrict__ b2,
            float* __restrict__ out) {
  __shared__ float w2L[256];
  w2L[threadIdx.x] = w2[threadIdx.x];
  __syncthreads();
  int k = blockIdx.x * 256 + threadIdx.x;
  if (k >= nE) return;
  int eid = csr_eid[k];
  if (eid < 0) return;                   // self loop, no bond output
  int s = csr_src[k], d = csr_dst[k];
  const ushort_t* Ur = U + (size_t)s * 64;
  const ushort_t* Vr = V + (size_t)d * 64;
  float l0 = b2[0], l1 = b2[1], l2 = b2[2], l3 = b2[3];
  #pragma unroll
  for (int c8 = 0; c8 < 8; ++c8) {
    u16x8 u = *(const u16x8*)(Ur + c8 * 8);
    u16x8 v = *(const u16x8*)(Vr + c8 * 8);
    #pragma unroll
    for (int j = 0; j < 8; ++j) {
      float h = fmaxf(bf2f(u[j]) + bf2f(v[j]), 0.f);
      const float* wr = &w2L[(c8 * 8 + j) * 4];
      l0 = fmaf(h, wr[0], l0);
      l1 = fmaf(h, wr[1], l1);
      l2 = fmaf(h, wr[2], l2);
      l3 = fmaf(h, wr[3], l3);
    }
  }
  float4 o = {l0, l1, l2, l3};
  *(float4*)&out[(size_t)eid * 4] = o;
}

extern "C" void kernel_launch(void* const* d_in, const int* in_sizes, int n_in,
                              void* d_out, int out_size, void* d_ws, size_t ws_size,
                              hipStream_t stream) {
  const float* x_t   = (const float*)d_in[0];
  const float* pos   = (const float*)d_in[1];
  const int*   ei    = (const int*)d_in[2];
  const int*   tt    = (const int*)d_in[3];
  const float* cond  = (const float*)d_in[4];
  const float* te_w1 = (const float*)d_in[5];
  const float* te_b1 = (const float*)d_in[6];
  const float* te_w2 = (const float*)d_in[7];
  const float* te_b2 = (const float*)d_in[8];
  const float* l1_nm_w1 = (const float*)d_in[9];
  const float* l1_nm_b1 = (const float*)d_in[10];
  const float* l1_nm_w2 = (const float*)d_in[11];
  const float* l1_nm_b2 = (const float*)d_in[12];
  const float* l1_cm_w1 = (const float*)d_in[13];
  const float* l1_cm_b1 = (const float*)d_in[14];
  const float* l1_cm_w2 = (const float*)d_in[15];
  const float* l1_cm_b2 = (const float*)d_in[16];
  const float* l2_nm_w1 = (const float*)d_in[17];
  const float* l2_nm_b1 = (const float*)d_in[18];
  const float* l2_nm_w2 = (const float*)d_in[19];
  const float* l2_nm_b2 = (const float*)d_in[20];
  const float* bp_w1 = (const float*)d_in[25];
  const float* bp_b1 = (const float*)d_in[26];
  const float* bp_w2 = (const float*)d_in[27];
  const float* bp_b2 = (const float*)d_in[28];

  int n  = in_sizes[0] / 64;
  int E_ = in_sizes[2] / 2;
  int nE = E_ + n;
  int nb = (n + 255) / 256;

  uintptr_t base = (uintptr_t)d_ws;
  size_t off = 0;
  auto alloc = [&](size_t bytes) -> void* {
    void* p = (void*)(base + off);
    off += (bytes + 255) & ~(size_t)255;
    return p;
  };
  float* t_emb = (float*)alloc(32 * 4);
  short* pk    = (short*)alloc(114688 * 2);
  short* pk_l1_t = pk;                  // +pk_l1_m adjacent (dual)
  short* pk_l1_2 = pk + 32768;
  short* pk_l2_t = pk + 49152;          // +pk_l2_m adjacent (dual)
  short* pk_l2_2 = pk + 81920;
  short* pk_bp_t = pk + 98304;          // +pk_bp_b adjacent (dual)
  ushort_t* X0b = (ushort_t*)alloc((size_t)n * 128 * 2);
  ushort_t* X1b = (ushort_t*)alloc((size_t)n * 128 * 2);
  ushort_t* Sb  = (ushort_t*)alloc((size_t)n * 128 * 2);
  ushort_t* Pbf = (ushort_t*)alloc((size_t)n * 128 * 2);
  ushort_t* Qbf = (ushort_t*)alloc((size_t)n * 128 * 2);
  int*   deg    = (int*)alloc((size_t)n * 4);
  int*   tmp    = (int*)alloc((size_t)n * 4);
  int*   bsum   = (int*)alloc(256 * 4);
  int*   rowp   = (int*)alloc(((size_t)n + 1) * 4);
  int*   cursor = (int*)alloc((size_t)n * 128);     // padded: 1 counter / 128B line
  int*   perm   = (int*)alloc((size_t)nE * 4);
  int*   csrsrc = (int*)alloc((size_t)nE * 4);
  int*   csrdst = (int*)alloc((size_t)nE * 4);
  int*   csreid = (int*)alloc((size_t)nE * 4);
  float4* aux4  = (float4*)alloc((size_t)nE * 16);
  float* degf   = (float*)alloc((size_t)n * 4);
  float* pos1   = (float*)alloc((size_t)n * 3 * 4);
  ushort_t* Ubf = Pbf;           // reuse after layer-2 aggregate
  ushort_t* Vbf = Qbf;

  // packs + time embed (fused) / input assembly
  k_pack_all<<<449, 256, 0, stream>>>(l1_nm_w1, l1_nm_w1 + 16384, l1_nm_w2,
                                      l2_nm_w1, l2_nm_w1 + 16384, l2_nm_w2,
                                      bp_w1, bp_w1 + 128 * 64, pk,
                                      tt, te_w1, te_b1, te_w2, te_b2, t_emb);
  k_build_xin<<<(n * 16 + 255) / 256, 256, 0, stream>>>(x_t, cond, t_emb, X0b, n);

  // CSR by dst: perm-scatter (1 random 4B store) + sequential fill (+ layer-1 aux)
  k_deg_init<<<nb, 256, 0, stream>>>(deg, n);
  k_deg_count<<<(E_ + 255) / 256, 256, 0, stream>>>(ei + E_, E_, deg);
  k_scan1<<<nb, 256, 0, stream>>>(deg, tmp, bsum, n);
  k_scan2<<<1, 256, 0, stream>>>(bsum, nb);
  k_scan3<<<nb, 256, 0, stream>>>(deg, tmp, bsum, rowp, cursor, n);
  k_scatter<<<(nE + 255) / 256, 256, 0, stream>>>(ei, E_, nE, cursor, perm);
  k_fill<<<(nE + 255) / 256, 256, 0, stream>>>(perm, ei, E_, nE, pos,
      l1_cm_w1, l1_cm_b1, l1_cm_w2, l1_cm_b2, csrsrc, csrdst, csreid, aux4);

  int nagg = (n + 3) / 4;
  int ngemm = (((n + 15) >> 4) + 3) / 4;     // 1 tile per wave exactly

  // ---- layer 1
  k_mgemm_dual<128><<<ngemm, 256, 0, stream>>>(X0b, pk_l1_t, l1_nm_b1, Pbf, Qbf, n);
  k_aggregate<true><<<nagg, 256, 0, stream>>>(rowp, csrsrc, aux4, Pbf, Qbf,
      l1_nm_w1 + 256 * 128, pos, pos1, degf, Sb, n);
  k_mgemm<128,true><<<ngemm, 256, 0, stream>>>(Sb, pk_l1_2, l1_nm_b2, X0b, degf, X1b, nullptr, n);

  // ---- layer 2 (pos2 dead -> no coord path; dist fused into aggregate)
  k_mgemm_dual<128><<<ngemm, 256, 0, stream>>>(X1b, pk_l2_t, l2_nm_b1, Pbf, Qbf, n);
  k_aggregate<false><<<nagg, 256, 0, stream>>>(rowp, csrsrc, nullptr, Pbf, Qbf,
      l2_nm_w1 + 256 * 128, pos1, nullptr, nullptr, Sb, n);
  // final post-GEMM writes X0b (bf16, feeds bond) AND d_out[:, :64] (f32)
  k_mgemm<128,true><<<ngemm, 256, 0, stream>>>(Sb, pk_l2_2, l2_nm_b2, X1b, degf, X0b, (float*)d_out, n);

  // ---- bond predictor (U,V bf16, reuse P/Q buffers), CSR order
  k_mgemm_dual<64><<<ngemm, 256, 0, stream>>>(X0b, pk_bp_t, bp_b1, Ubf, Vbf, n);
  k_bond<<<(nE + 255) / 256, 256, 0, stream>>>(csrsrc, csrdst, csreid, nE, Ubf, Vbf,
                                               bp_w2, bp_b2, (float*)d_out + (size_t)n * 64);
}

// Round 14
// 315.819 us; speedup vs baseline: 1.3076x; 1.3076x over previous
//
#include <hip/hip_runtime.h>
#include <hip/hip_bf16.h>
#include <stdint.h>

typedef float  f32x4 __attribute__((ext_vector_type(4)));
typedef short  s16x8 __attribute__((ext_vector_type(8)));
typedef unsigned short u16x8 __attribute__((ext_vector_type(8)));
typedef unsigned short ushort_t;

__device__ __forceinline__ short f2bf(float f) {
  union { float f; unsigned u; } x; x.f = f;
  unsigned r = x.u + 0x7fffu + ((x.u >> 16) & 1u);
  return (short)(r >> 16);
}
__device__ __forceinline__ float bf2f(unsigned short u) {
  union { unsigned u; float f; } x; x.u = ((unsigned)u) << 16; return x.f;
}

__device__ __forceinline__ void pack_one(const float* W, int cols, int local, short* dst) {
  int NT = cols / 16;
  int j = local & 7, l = (local >> 3) & 63;
  int nt = (local >> 9) % NT;
  int kt = (local >> 9) / NT;
  int k = kt * 32 + ((l >> 4) * 8) + j;
  int ncol = nt * 16 + (l & 15);
  dst[local] = f2bf(W[(size_t)k * cols + ncol]);
}

// ---------------- front: weight pack + build_xin (temb in-block) + deg_count
__global__ __launch_bounds__(256)
void k_front(const float* __restrict__ w0, const float* __restrict__ w1,
             const float* __restrict__ w2, const float* __restrict__ w3,
             const float* __restrict__ w4, const float* __restrict__ w5,
             const float* __restrict__ w6, const float* __restrict__ w7,
             short* __restrict__ out,
             const int* __restrict__ t, const float* __restrict__ tw1,
             const float* __restrict__ tb1, const float* __restrict__ tw2,
             const float* __restrict__ tb2,
             const float* __restrict__ xt, const float* __restrict__ cond,
             ushort_t* __restrict__ X, int n,
             const int* __restrict__ edst, int E, int* __restrict__ deg,
             int nbBuild) {
  int b = blockIdx.x;
  if (b < 448) {                       // pack: 448*256 = 114688 elements exactly
    int i = b * 256 + threadIdx.x;
    if (i < 98304) {
      int r = i >> 14, local = i & 16383;
      const float* W = r == 0 ? w0 : r == 1 ? w1 : r == 2 ? w2 : r == 3 ? w3 : r == 4 ? w4 : w5;
      pack_one(W, 128, local, out + r * 16384);
    } else {
      int j = i - 98304;
      int r = j >> 13, local = j & 8191;
      pack_one(r ? w7 : w6, 64, local, out + 98304 + r * 8192);
    }
    return;
  }
  b -= 448;
  if (b < nbBuild) {                   // build_xin, temb computed per-block in LDS
    __shared__ float h[32], tembL[32];
    int j = threadIdx.x;
    if (j < 32) h[j] = fmaxf(((float)t[0] / 1000.0f) * tw1[j] + tb1[j], 0.f);
    __syncthreads();
    if (j < 32) {
      float acc = tb2[j];
      for (int k2 = 0; k2 < 32; ++k2) acc += h[k2] * tw2[k2 * 32 + j];
      tembL[j] = acc;
    }
    __syncthreads();
    int i = b * 256 + threadIdx.x;
    if (i >= n * 16) return;
    int node = i >> 4, c8 = i & 15;
    float va[8];
    if (c8 < 8)       { const float* p = &xt[(size_t)node * 64 + c8 * 8];
                        #pragma unroll
                        for (int q = 0; q < 8; ++q) va[q] = p[q]; }
    else if (c8 < 12) { const float* p = &cond[(c8 - 8) * 8];
                        #pragma unroll
                        for (int q = 0; q < 8; ++q) va[q] = p[q]; }
    else              { const float* p = &tembL[(c8 - 12) * 8];
                        #pragma unroll
                        for (int q = 0; q < 8; ++q) va[q] = p[q]; }
    u16x8 o;
    #pragma unroll
    for (int q = 0; q < 8; ++q) o[q] = f2bf(va[q]);
    *(u16x8*)&X[(size_t)node * 128 + c8 * 8] = o;
    return;
  }
  b -= nbBuild;                        // deg_count (deg pre-zeroed by memset)
  int e = b * 256 + threadIdx.x;
  if (e < E) atomicAdd(&deg[edst[e]], 1);
}

// ---------------- scans (self-loop +1 folded in)
__global__ void k_scan1(const int* __restrict__ deg, int* __restrict__ tmp,
                        int* __restrict__ bsum, int n) {
  __shared__ int sh[256];
  int i = blockIdx.x * 256 + threadIdx.x;
  int v = (i < n) ? deg[i] + 1 : 0;
  sh[threadIdx.x] = v; __syncthreads();
  for (int off = 1; off < 256; off <<= 1) {
    int t = (threadIdx.x >= off) ? sh[threadIdx.x - off] : 0;
    __syncthreads();
    sh[threadIdx.x] += t;
    __syncthreads();
  }
  if (i < n) tmp[i] = sh[threadIdx.x];
  if (threadIdx.x == 255) bsum[blockIdx.x] = sh[255];
}
__global__ void k_scan2(int* __restrict__ bsum, int nb) {
  __shared__ int sh[256];
  int t = threadIdx.x;
  int v = (t < nb) ? bsum[t] : 0;
  sh[t] = v; __syncthreads();
  for (int off = 1; off < 256; off <<= 1) {
    int u = (t >= off) ? sh[t - off] : 0;
    __syncthreads();
    sh[t] += u;
    __syncthreads();
  }
  if (t < nb) bsum[t] = sh[t] - v;
}
__global__ void k_scan3(const int* __restrict__ deg, const int* __restrict__ tmp,
                        const int* __restrict__ bsum, int* __restrict__ row,
                        int* __restrict__ cursor, int n) {
  int i = blockIdx.x * 256 + threadIdx.x;
  if (i < n) {
    int incl = tmp[i] + bsum[i >> 8];
    row[i + 1] = incl;
    cursor[(size_t)i * 32] = incl - (deg[i] + 1);
    if (i == 0) row[0] = 0;
  }
}

// ---------------- hybrid: layer-1 dual GEMM (blocks < ngemm) || scatter+aux1
__global__ __launch_bounds__(256)
void k_dual_scatter(const ushort_t* __restrict__ A, const short* __restrict__ Wp,
                    const float* __restrict__ bias1,
                    ushort_t* __restrict__ out1, ushort_t* __restrict__ out2,
                    int n, int ngemm,
                    const int* __restrict__ ei, int E, int nE,
                    int* __restrict__ cursor,
                    int* __restrict__ csr_src, int* __restrict__ csr_dst,
                    int* __restrict__ csr_eid,
                    const float* __restrict__ pos,
                    const float* __restrict__ cw1, const float* __restrict__ cb1,
                    const float* __restrict__ cw2, const float* __restrict__ cb2,
                    float4* __restrict__ aux) {
  __shared__ short BL[2 * 128 * 128];
  if ((int)blockIdx.x < ngemm) {
    const int NT = 8;
    for (int i = threadIdx.x; i < 4096; i += 256)
      ((int4*)BL)[i] = ((const int4*)Wp)[i];
    __syncthreads();
    int t = threadIdx.x, wid = t >> 6, lane = t & 63;
    int cg = lane >> 4;
    float bb[NT];
    #pragma unroll
    for (int nt = 0; nt < NT; ++nt)
      bb[nt] = bias1 ? bias1[nt * 16 + (lane & 15)] : 0.f;
    int ntiles = (n + 15) >> 4;
    int tile = blockIdx.x * 4 + wid;
    if (tile >= ntiles) return;
    int r0 = tile << 4;
    int arow = r0 + (lane & 15);
    int crow = arow < n ? arow : 0;
    const ushort_t* Ar = A + (size_t)crow * 128;
    s16x8 Af[4];
    #pragma unroll
    for (int kt = 0; kt < 4; ++kt)
      Af[kt] = *(const s16x8*)(Ar + kt * 32 + cg * 8);
    #pragma unroll
    for (int w = 0; w < 2; ++w) {
      ushort_t* outp = w ? out2 : out1;
      #pragma unroll
      for (int nt = 0; nt < NT; ++nt) {
        f32x4 acc = {0.f, 0.f, 0.f, 0.f};
        #pragma unroll
        for (int kt = 0; kt < 4; ++kt) {
          s16x8 bfr = *(const s16x8*)&BL[(w * 2048 + (kt * NT + nt) * 64 + lane) * 8];
          acc = __builtin_amdgcn_mfma_f32_16x16x32_bf16(Af[kt], bfr, acc, 0, 0, 0);
        }
        int ncol = nt * 16 + (lane & 15);
        float badd = w ? 0.f : bb[nt];
        #pragma unroll
        for (int reg = 0; reg < 4; ++reg) {
          int rr = r0 + cg * 4 + reg;
          if (rr < n)
            outp[(size_t)rr * 128 + ncol] = (ushort_t)f2bf(acc[reg] + badd);
        }
      }
    }
    return;
  }
  // ---- scatter + fused layer-1 aux
  int e = (blockIdx.x - ngemm) * 256 + threadIdx.x;
  if (e >= nE) return;
  int s, d, id;
  if (e < E) { s = ei[e]; d = ei[E + e]; id = e; }
  else       { s = d = e - E; id = -1; }
  int slot = atomicAdd(&cursor[(size_t)d * 32], 1);
  csr_src[slot] = s;
  csr_dst[slot] = d;
  csr_eid[slot] = id;
  float dx = pos[s*3+0] - pos[d*3+0];
  float dy = pos[s*3+1] - pos[d*3+1];
  float dz = pos[s*3+2] - pos[d*3+2];
  float dist = sqrtf(dx*dx + dy*dy + dz*dz + 1e-8f);
  float hh = cb2[0];
  #pragma unroll 4
  for (int j = 0; j < 128; ++j)
    hh += fmaxf(fmaf(dist, cw1[j], cb1[j]), 0.f) * cw2[j];
  float4 o; o.x = dist; o.y = hh * dx; o.z = hh * dy; o.w = hh * dz;
  aux[slot] = o;
}

// ---------------- single node GEMM (also used in hybrid below)
__device__ __forceinline__
void mgemm_body(const ushort_t* A, const short* Wp, const float* bias,
                const ushort_t* resid, const float* degf, ushort_t* out,
                float* out64, int n, int bid, short* BL) {
  const int NT = 8;
  for (int i = threadIdx.x; i < 2048; i += 256)
    ((int4*)BL)[i] = ((const int4*)Wp)[i];
  __syncthreads();
  int t = threadIdx.x, wid = t >> 6, lane = t & 63;
  int cg = lane >> 4;
  float bb[NT];
  #pragma unroll
  for (int nt = 0; nt < NT; ++nt)
    bb[nt] = bias ? bias[nt * 16 + (lane & 15)] : 0.f;
  int ntiles = (n + 15) >> 4;
  int tile = bid * 4 + wid;
  if (tile >= ntiles) return;
  int r0 = tile << 4;
  int arow = r0 + (lane & 15);
  int crow = arow < n ? arow : 0;
  const ushort_t* Ar = A + (size_t)crow * 128;
  s16x8 Af[4];
  #pragma unroll
  for (int kt = 0; kt < 4; ++kt)
    Af[kt] = *(const s16x8*)(Ar + kt * 32 + cg * 8);
  float dsc[4];
  #pragma unroll
  for (int reg = 0; reg < 4; ++reg) {
    int rr = r0 + cg * 4 + reg;
    dsc[reg] = degf ? degf[rr < n ? rr : 0] : 1.f;
  }
  #pragma unroll
  for (int nt = 0; nt < NT; ++nt) {
    f32x4 acc = {0.f, 0.f, 0.f, 0.f};
    #pragma unroll
    for (int kt = 0; kt < 4; ++kt) {
      s16x8 bfr = *(const s16x8*)&BL[((kt * NT + nt) * 64 + lane) * 8];
      acc = __builtin_amdgcn_mfma_f32_16x16x32_bf16(Af[kt], bfr, acc, 0, 0, 0);
    }
    int ncol = nt * 16 + (lane & 15);
    #pragma unroll
    for (int reg = 0; reg < 4; ++reg) {
      int rr = r0 + cg * 4 + reg;
      if (rr < n) {
        float v = acc[reg] + dsc[reg] * bb[nt];
        if (resid) v += bf2f(resid[(size_t)rr * 128 + ncol]);
        out[(size_t)rr * 128 + ncol] = (ushort_t)f2bf(v);
        if (out64 && ncol < 64) out64[(size_t)rr * 64 + ncol] = v;
      }
    }
  }
}

__global__ __launch_bounds__(256)
void k_mgemm(const ushort_t* __restrict__ A, const short* __restrict__ Wp,
             const float* __restrict__ bias, const ushort_t* __restrict__ resid,
             const float* __restrict__ degf, ushort_t* __restrict__ out,
             float* __restrict__ out64, int n) {
  __shared__ short BL[128 * 128];
  mgemm_body(A, Wp, bias, resid, degf, out, out64, n, blockIdx.x, BL);
}

// hybrid: post-GEMM layer1 (blocks < ngemm) || aux2 (dist for layer 2)
__global__ __launch_bounds__(256)
void k_post_aux(const ushort_t* __restrict__ A, const short* __restrict__ Wp,
                const float* __restrict__ bias, const ushort_t* __restrict__ resid,
                const float* __restrict__ degf, ushort_t* __restrict__ out,
                int n, int ngemm,
                const int* __restrict__ csr_src, const int* __restrict__ csr_dst,
                int nE, const float* __restrict__ pos1, float* __restrict__ auxd) {
  __shared__ short BL[128 * 128];
  if ((int)blockIdx.x < ngemm) {
    mgemm_body(A, Wp, bias, resid, degf, out, nullptr, n, blockIdx.x, BL);
    return;
  }
  int k = (blockIdx.x - ngemm) * 256 + threadIdx.x;
  if (k >= nE) return;
  int s = csr_src[k], d = csr_dst[k];
  float dx = pos1[s*3+0] - pos1[d*3+0];
  float dy = pos1[s*3+1] - pos1[d*3+1];
  float dz = pos1[s*3+2] - pos1[d*3+2];
  auxd[k] = sqrtf(dx*dx + dy*dy + dz*dz + 1e-8f);
}

// ---------------- dual node GEMM (layer 2 pre + bond pre)
template<int COLS>
__global__ __launch_bounds__(256)
void k_mgemm_dual(const ushort_t* __restrict__ A, const short* __restrict__ Wp,
                  const float* __restrict__ bias1,
                  ushort_t* __restrict__ out1, ushort_t* __restrict__ out2, int n) {
  const int NT = COLS / 16;
  __shared__ short BL[2 * 128 * COLS];
  for (int i = threadIdx.x; i < 2 * 128 * COLS / 8; i += 256)
    ((int4*)BL)[i] = ((const int4*)Wp)[i];
  __syncthreads();
  int t = threadIdx.x, wid = t >> 6, lane = t & 63;
  int cg = lane >> 4;
  float bb[NT];
  #pragma unroll
  for (int nt = 0; nt < NT; ++nt)
    bb[nt] = bias1 ? bias1[nt * 16 + (lane & 15)] : 0.f;
  int ntiles = (n + 15) >> 4;
  for (int tile = blockIdx.x * 4 + wid; tile < ntiles; tile += gridDim.x * 4) {
    int r0 = tile << 4;
    int arow = r0 + (lane & 15);
    int crow = arow < n ? arow : 0;
    const ushort_t* Ar = A + (size_t)crow * 128;
    s16x8 Af[4];
    #pragma unroll
    for (int kt = 0; kt < 4; ++kt)
      Af[kt] = *(const s16x8*)(Ar + kt * 32 + cg * 8);
    #pragma unroll
    for (int w = 0; w < 2; ++w) {
      ushort_t* outp = w ? out2 : out1;
      #pragma unroll
      for (int nt = 0; nt < NT; ++nt) {
        f32x4 acc = {0.f, 0.f, 0.f, 0.f};
        #pragma unroll
        for (int kt = 0; kt < 4; ++kt) {
          s16x8 bfr = *(const s16x8*)&BL[(w * 128 * COLS / 8 + (kt * NT + nt) * 64 + lane) * 8];
          acc = __builtin_amdgcn_mfma_f32_16x16x32_bf16(Af[kt], bfr, acc, 0, 0, 0);
        }
        int ncol = nt * 16 + (lane & 15);
        float badd = w ? 0.f : bb[nt];
        #pragma unroll
        for (int reg = 0; reg < 4; ++reg) {
          int rr = r0 + cg * 4 + reg;
          if (rr < n)
            outp[(size_t)rr * COLS + ncol] = (ushort_t)f2bf(acc[reg] + badd);
        }
      }
    }
  }
}

// ---------------- per-dst aggregation: one wave per node, TWO 32-lane half-streams (r12)
template<bool L1>
__global__ __launch_bounds__(256)
void k_aggregate(const int* __restrict__ row, const int* __restrict__ csr_src,
                 const float4* __restrict__ aux4, const float* __restrict__ auxd,
                 const ushort_t* __restrict__ Pb, const ushort_t* __restrict__ Qb,
                 const float* __restrict__ w1r,
                 const float* __restrict__ posin, float* __restrict__ posout,
                 float* __restrict__ degf, ushort_t* __restrict__ Sb, int n) {
  int gw = (blockIdx.x * 256 + threadIdx.x) >> 6;
  if (gw >= n) return;
  int lane = threadIdx.x & 63;
  int half = lane >> 5, sub = lane & 31;
  int r0 = row[gw], r1 = row[gw + 1];
  int r1m1 = r1 - 1;

  ushort4 pu = *(const ushort4*)&Pb[(size_t)gw * 128 + (sub << 2)];
  float p0 = bf2f(pu.x), p1 = bf2f(pu.y), p2 = bf2f(pu.z), p3 = bf2f(pu.w);
  float4 wv = *(const float4*)&w1r[sub << 2];
  float a0 = 0.f, a1 = 0.f, a2 = 0.f, a3 = 0.f, pacc = 0.f;

  int k0 = r0 + half;
  bool any = k0 < r1;
  int kA = k0 < r1m1 ? k0 : r1m1;
  int kB = k0 + 2 < r1m1 ? k0 + 2 : r1m1;
  int sA = csr_src[kA];
  int sB = csr_src[kB];
  ushort4 qA = *(const ushort4*)&Qb[(size_t)sA * 128 + (sub << 2)];
  float4 axA, axB;
  if (L1) axA = aux4[kA]; else { axA.x = auxd[kA]; axA.y = axA.z = axA.w = 0.f; }

  for (int k = k0; k + 2 < r1; k += 2) {
    int kn4 = k + 4 < r1m1 ? k + 4 : r1m1;
    int sC = csr_src[kn4];
    ushort4 qB = *(const ushort4*)&Qb[(size_t)sB * 128 + (sub << 2)];
    if (L1) axB = aux4[k + 2]; else { axB.x = auxd[k + 2]; axB.y = axB.z = axB.w = 0.f; }
    a0 += fmaxf(fmaf(axA.x, wv.x, p0 + bf2f(qA.x)), 0.f);
    a1 += fmaxf(fmaf(axA.x, wv.y, p1 + bf2f(qA.y)), 0.f);
    a2 += fmaxf(fmaf(axA.x, wv.z, p2 + bf2f(qA.z)), 0.f);
    a3 += fmaxf(fmaf(axA.x, wv.w, p3 + bf2f(qA.w)), 0.f);
    if (L1 && sub < 3) pacc += (sub == 0) ? axA.y : (sub == 1) ? axA.z : axA.w;
    qA = qB; axA = axB; sB = sC;
  }
  if (any) {
    a0 += fmaxf(fmaf(axA.x, wv.x, p0 + bf2f(qA.x)), 0.f);
    a1 += fmaxf(fmaf(axA.x, wv.y, p1 + bf2f(qA.y)), 0.f);
    a2 += fmaxf(fmaf(axA.x, wv.z, p2 + bf2f(qA.z)), 0.f);
    a3 += fmaxf(fmaf(axA.x, wv.w, p3 + bf2f(qA.w)), 0.f);
    if (L1 && sub < 3) pacc += (sub == 0) ? axA.y : (sub == 1) ? axA.z : axA.w;
  }

  a0 += __shfl_xor(a0, 32, 64);
  a1 += __shfl_xor(a1, 32, 64);
  a2 += __shfl_xor(a2, 32, 64);
  a3 += __shfl_xor(a3, 32, 64);
  if (L1) pacc += __shfl_xor(pacc, 32, 64);

  if (half == 0) {
    ushort4 o;
    o.x = (ushort_t)f2bf(a0); o.y = (ushort_t)f2bf(a1);
    o.z = (ushort_t)f2bf(a2); o.w = (ushort_t)f2bf(a3);
    *(ushort4*)&Sb[(size_t)gw * 128 + (sub << 2)] = o;
  }
  if (L1) {
    if (lane < 3) posout[gw * 3 + lane] = posin[gw * 3 + lane] + pacc;
    if (lane == 0) degf[gw] = (float)(r1 - r0);
  }
}

// ---------------- bond predictor in CSR(dst) order
__global__ __launch_bounds__(256)
void k_bond(const int* __restrict__ csr_src, const int* __restrict__ csr_dst,
            const int* __restrict__ csr_eid, int nE,
            const ushort_t* __restrict__ U, const ushort_t* __restrict__ V,
            const float* __restrict__ w2, const float* __restrict__ b2,
            float* __restrict__ out) {
  __shared__ float w2L[256];
  w2L[threadIdx.x] = w2[threadIdx.x];
  __syncthreads();
  int k = blockIdx.x * 256 + threadIdx.x;
  if (k >= nE) return;
  int eid = csr_eid[k];
  if (eid < 0) return;
  int s = csr_src[k], d = csr_dst[k];
  const ushort_t* Ur = U + (size_t)s * 64;
  const ushort_t* Vr = V + (size_t)d * 64;
  float l0 = b2[0], l1 = b2[1], l2 = b2[2], l3 = b2[3];
  #pragma unroll
  for (int c8 = 0; c8 < 8; ++c8) {
    u16x8 u = *(const u16x8*)(Ur + c8 * 8);
    u16x8 v = *(const u16x8*)(Vr + c8 * 8);
    #pragma unroll
    for (int j = 0; j < 8; ++j) {
      float h = fmaxf(bf2f(u[j]) + bf2f(v[j]), 0.f);
      const float* wr = &w2L[(c8 * 8 + j) * 4];
      l0 = fmaf(h, wr[0], l0);
      l1 = fmaf(h, wr[1], l1);
      l2 = fmaf(h, wr[2], l2);
      l3 = fmaf(h, wr[3], l3);
    }
  }
  float4 o = {l0, l1, l2, l3};
  *(float4*)&out[(size_t)eid * 4] = o;
}

extern "C" void kernel_launch(void* const* d_in, const int* in_sizes, int n_in,
                              void* d_out, int out_size, void* d_ws, size_t ws_size,
                              hipStream_t stream) {
  const float* x_t   = (const float*)d_in[0];
  const float* pos   = (const float*)d_in[1];
  const int*   ei    = (const int*)d_in[2];
  const int*   tt    = (const int*)d_in[3];
  const float* cond  = (const float*)d_in[4];
  const float* te_w1 = (const float*)d_in[5];
  const float* te_b1 = (const float*)d_in[6];
  const float* te_w2 = (const float*)d_in[7];
  const float* te_b2 = (const float*)d_in[8];
  const float* l1_nm_w1 = (const float*)d_in[9];
  const float* l1_nm_b1 = (const float*)d_in[10];
  const float* l1_nm_w2 = (const float*)d_in[11];
  const float* l1_nm_b2 = (const float*)d_in[12];
  const float* l1_cm_w1 = (const float*)d_in[13];
  const float* l1_cm_b1 = (const float*)d_in[14];
  const float* l1_cm_w2 = (const float*)d_in[15];
  const float* l1_cm_b2 = (const float*)d_in[16];
  const float* l2_nm_w1 = (const float*)d_in[17];
  const float* l2_nm_b1 = (const float*)d_in[18];
  const float* l2_nm_w2 = (const float*)d_in[19];
  const float* l2_nm_b2 = (const float*)d_in[20];
  const float* bp_w1 = (const float*)d_in[25];
  const float* bp_b1 = (const float*)d_in[26];
  const float* bp_w2 = (const float*)d_in[27];
  const float* bp_b2 = (const float*)d_in[28];

  int n  = in_sizes[0] / 64;
  int E_ = in_sizes[2] / 2;
  int nE = E_ + n;
  int nb = (n + 255) / 256;

  uintptr_t base = (uintptr_t)d_ws;
  size_t off = 0;
  auto alloc = [&](size_t bytes) -> void* {
    void* p = (void*)(base + off);
    off += (bytes + 255) & ~(size_t)255;
    return p;
  };
  short* pk    = (short*)alloc(114688 * 2);
  short* pk_l1_t = pk;
  short* pk_l1_2 = pk + 32768;
  short* pk_l2_t = pk + 49152;
  short* pk_l2_2 = pk + 81920;
  short* pk_bp_t = pk + 98304;
  ushort_t* X0b = (ushort_t*)alloc((size_t)n * 128 * 2);
  ushort_t* X1b = (ushort_t*)alloc((size_t)n * 128 * 2);
  ushort_t* Sb  = (ushort_t*)alloc((size_t)n * 128 * 2);
  ushort_t* Pbf = (ushort_t*)alloc((size_t)n * 128 * 2);
  ushort_t* Qbf = (ushort_t*)alloc((size_t)n * 128 * 2);
  int*   deg    = (int*)alloc((size_t)n * 4);
  int*   tmp    = (int*)alloc((size_t)n * 4);
  int*   bsum   = (int*)alloc(256 * 4);
  int*   rowp   = (int*)alloc(((size_t)n + 1) * 4);
  int*   cursor = (int*)alloc((size_t)n * 128);     // 1 counter / 128B line
  int*   csrsrc = (int*)alloc((size_t)nE * 4);
  int*   csrdst = (int*)alloc((size_t)nE * 4);
  int*   csreid = (int*)alloc((size_t)nE * 4);
  float4* aux4  = (float4*)alloc((size_t)nE * 16);
  float* auxd   = (float*)alloc((size_t)nE * 4);
  float* degf   = (float*)alloc((size_t)n * 4);
  float* pos1   = (float*)alloc((size_t)n * 3 * 4);
  ushort_t* Ubf = Pbf;
  ushort_t* Vbf = Qbf;

  int nbBuild = (n * 16 + 255) / 256;
  int ndc = (E_ + 255) / 256;
  int nscat = (nE + 255) / 256;
  int nagg = (n + 3) / 4;
  int ngemm = (((n + 15) >> 4) + 3) / 4;

  // front: memset deg, then pack + build_xin + deg_count in one launch
  hipMemsetAsync(deg, 0, (size_t)n * 4, stream);
  k_front<<<448 + nbBuild + ndc, 256, 0, stream>>>(
      l1_nm_w1, l1_nm_w1 + 16384, l1_nm_w2, l2_nm_w1, l2_nm_w1 + 16384, l2_nm_w2,
      bp_w1, bp_w1 + 128 * 64, pk,
      tt, te_w1, te_b1, te_w2, te_b2,
      x_t, cond, X0b, n, ei + E_, E_, deg, nbBuild);
  k_scan1<<<nb, 256, 0, stream>>>(deg, tmp, bsum, n);
  k_scan2<<<1, 256, 0, stream>>>(bsum, nb);
  k_scan3<<<nb, 256, 0, stream>>>(deg, tmp, bsum, rowp, cursor, n);

  // layer-1 dual GEMM || scatter+aux1 (independent -> one hybrid launch)
  k_dual_scatter<<<ngemm + nscat, 256, 0, stream>>>(
      X0b, pk_l1_t, l1_nm_b1, Pbf, Qbf, n, ngemm,
      ei, E_, nE, cursor, csrsrc, csrdst, csreid,
      pos, l1_cm_w1, l1_cm_b1, l1_cm_w2, l1_cm_b2, aux4);

  k_aggregate<true><<<nagg, 256, 0, stream>>>(rowp, csrsrc, aux4, nullptr, Pbf, Qbf,
      l1_nm_w1 + 256 * 128, pos, pos1, degf, Sb, n);

  // post-GEMM layer1 || aux2 (both depend only on agg1)
  k_post_aux<<<ngemm + nscat, 256, 0, stream>>>(
      Sb, pk_l1_2, l1_nm_b2, X0b, degf, X1b, n, ngemm,
      csrsrc, csrdst, nE, pos1, auxd);

  // layer 2
  k_mgemm_dual<128><<<ngemm, 256, 0, stream>>>(X1b, pk_l2_t, l2_nm_b1, Pbf, Qbf, n);
  k_aggregate<false><<<nagg, 256, 0, stream>>>(rowp, csrsrc, nullptr, auxd, Pbf, Qbf,
      l2_nm_w1 + 256 * 128, nullptr, nullptr, nullptr, Sb, n);
  k_mgemm<<<ngemm, 256, 0, stream>>>(Sb, pk_l2_2, l2_nm_b2, X1b, degf, X0b, (float*)d_out, n);

  // bond predictor
  k_mgemm_dual<64><<<ngemm, 256, 0, stream>>>(X0b, pk_bp_t, bp_b1, Ubf, Vbf, n);
  k_bond<<<nscat, 256, 0, stream>>>(csrsrc, csrdst, csreid, nE, Ubf, Vbf,
                                    bp_w2, bp_b2, (float*)d_out + (size_t)n * 64);
}

// Round 15
// 293.257 us; speedup vs baseline: 1.4082x; 1.0769x over previous
//
#include <hip/hip_runtime.h>
#include <hip/hip_bf16.h>
#include <stdint.h>

typedef float  f32x4 __attribute__((ext_vector_type(4)));
typedef short  s16x8 __attribute__((ext_vector_type(8)));
typedef unsigned short u16x8 __attribute__((ext_vector_type(8)));
typedef unsigned short ushort_t;

__device__ __forceinline__ short f2bf(float f) {
  union { float f; unsigned u; } x; x.f = f;
  unsigned r = x.u + 0x7fffu + ((x.u >> 16) & 1u);
  return (short)(r >> 16);
}
__device__ __forceinline__ float bf2f(unsigned short u) {
  union { unsigned u; float f; } x; x.u = ((unsigned)u) << 16; return x.f;
}

__device__ __forceinline__ void pack_one(const float* W, int cols, int local, short* dst) {
  int NT = cols / 16;
  int j = local & 7, l = (local >> 3) & 63;
  int nt = (local >> 9) % NT;
  int kt = (local >> 9) / NT;
  int k = kt * 32 + ((l >> 4) * 8) + j;
  int ncol = nt * 16 + (l & 15);
  dst[local] = f2bf(W[(size_t)k * cols + ncol]);
}

// ---------------- front: weight pack + build_xin (temb in-block) + deg_count
__global__ __launch_bounds__(256)
void k_front(const float* __restrict__ w0, const float* __restrict__ w1,
             const float* __restrict__ w2, const float* __restrict__ w3,
             const float* __restrict__ w4, const float* __restrict__ w5,
             const float* __restrict__ w6, const float* __restrict__ w7,
             short* __restrict__ out,
             const int* __restrict__ t, const float* __restrict__ tw1,
             const float* __restrict__ tb1, const float* __restrict__ tw2,
             const float* __restrict__ tb2,
             const float* __restrict__ xt, const float* __restrict__ cond,
             ushort_t* __restrict__ X, int n,
             const int* __restrict__ edst, int E, int* __restrict__ deg,
             int nbBuild) {
  int b = blockIdx.x;
  if (b < 448) {
    int i = b * 256 + threadIdx.x;
    if (i < 98304) {
      int r = i >> 14, local = i & 16383;
      const float* W = r == 0 ? w0 : r == 1 ? w1 : r == 2 ? w2 : r == 3 ? w3 : r == 4 ? w4 : w5;
      pack_one(W, 128, local, out + r * 16384);
    } else {
      int j = i - 98304;
      int r = j >> 13, local = j & 8191;
      pack_one(r ? w7 : w6, 64, local, out + 98304 + r * 8192);
    }
    return;
  }
  b -= 448;
  if (b < nbBuild) {
    __shared__ float h[32], tembL[32];
    int j = threadIdx.x;
    if (j < 32) h[j] = fmaxf(((float)t[0] / 1000.0f) * tw1[j] + tb1[j], 0.f);
    __syncthreads();
    if (j < 32) {
      float acc = tb2[j];
      for (int k2 = 0; k2 < 32; ++k2) acc += h[k2] * tw2[k2 * 32 + j];
      tembL[j] = acc;
    }
    __syncthreads();
    int i = b * 256 + threadIdx.x;
    if (i >= n * 16) return;
    int node = i >> 4, c8 = i & 15;
    float va[8];
    if (c8 < 8)       { const float* p = &xt[(size_t)node * 64 + c8 * 8];
                        #pragma unroll
                        for (int q = 0; q < 8; ++q) va[q] = p[q]; }
    else if (c8 < 12) { const float* p = &cond[(c8 - 8) * 8];
                        #pragma unroll
                        for (int q = 0; q < 8; ++q) va[q] = p[q]; }
    else              { const float* p = &tembL[(c8 - 12) * 8];
                        #pragma unroll
                        for (int q = 0; q < 8; ++q) va[q] = p[q]; }
    u16x8 o;
    #pragma unroll
    for (int q = 0; q < 8; ++q) o[q] = f2bf(va[q]);
    *(u16x8*)&X[(size_t)node * 128 + c8 * 8] = o;
    return;
  }
  b -= nbBuild;
  int e = b * 256 + threadIdx.x;
  if (e < E) atomicAdd(&deg[edst[e]], 1);
}

// ---------------- scans (self-loop +1 folded in)
__global__ void k_scan1(const int* __restrict__ deg, int* __restrict__ tmp,
                        int* __restrict__ bsum, int n) {
  __shared__ int sh[256];
  int i = blockIdx.x * 256 + threadIdx.x;
  int v = (i < n) ? deg[i] + 1 : 0;
  sh[threadIdx.x] = v; __syncthreads();
  for (int off = 1; off < 256; off <<= 1) {
    int t = (threadIdx.x >= off) ? sh[threadIdx.x - off] : 0;
    __syncthreads();
    sh[threadIdx.x] += t;
    __syncthreads();
  }
  if (i < n) tmp[i] = sh[threadIdx.x];
  if (threadIdx.x == 255) bsum[blockIdx.x] = sh[255];
}
__global__ void k_scan2(int* __restrict__ bsum, int nb) {
  __shared__ int sh[256];
  int t = threadIdx.x;
  int v = (t < nb) ? bsum[t] : 0;
  sh[t] = v; __syncthreads();
  for (int off = 1; off < 256; off <<= 1) {
    int u = (t >= off) ? sh[t - off] : 0;
    __syncthreads();
    sh[t] += u;
    __syncthreads();
  }
  if (t < nb) bsum[t] = sh[t] - v;
}
__global__ void k_scan3(const int* __restrict__ deg, const int* __restrict__ tmp,
                        const int* __restrict__ bsum, int* __restrict__ row,
                        int* __restrict__ cursor, int n) {
  int i = blockIdx.x * 256 + threadIdx.x;
  if (i < n) {
    int incl = tmp[i] + bsum[i >> 8];
    row[i + 1] = incl;
    cursor[(size_t)i * 32] = incl - (deg[i] + 1);
    if (i == 0) row[0] = 0;
  }
}

// dual-GEMM body, two-phase 32KB staging (A frags persist in regs)
__device__ __forceinline__
void dual_body(const ushort_t* A, const short* Wp, const float* bias1,
               ushort_t* out1, ushort_t* out2, int n, int bid, short* BL) {
  const int NT = 8;
  int t = threadIdx.x, wid = t >> 6, lane = t & 63;
  int cg = lane >> 4;
  int ntiles = (n + 15) >> 4;
  int tile = bid * 4 + wid;
  bool valid = tile < ntiles;
  int r0 = (valid ? tile : 0) << 4;
  int arow = r0 + (lane & 15);
  int crow = arow < n ? arow : 0;
  const ushort_t* Ar = A + (size_t)crow * 128;
  s16x8 Af[4];
  #pragma unroll
  for (int kt = 0; kt < 4; ++kt)
    Af[kt] = *(const s16x8*)(Ar + kt * 32 + cg * 8);
  float bb[NT];
  #pragma unroll
  for (int nt = 0; nt < NT; ++nt)
    bb[nt] = bias1 ? bias1[nt * 16 + (lane & 15)] : 0.f;
  #pragma unroll
  for (int w = 0; w < 2; ++w) {
    // stage this weight (32KB)
    for (int i = threadIdx.x; i < 2048; i += 256)
      ((int4*)BL)[i] = ((const int4*)Wp)[w * 2048 + i];
    __syncthreads();
    ushort_t* outp = w ? out2 : out1;
    #pragma unroll
    for (int nt = 0; nt < NT; ++nt) {
      f32x4 acc = {0.f, 0.f, 0.f, 0.f};
      #pragma unroll
      for (int kt = 0; kt < 4; ++kt) {
        s16x8 bfr = *(const s16x8*)&BL[((kt * NT + nt) * 64 + lane) * 8];
        acc = __builtin_amdgcn_mfma_f32_16x16x32_bf16(Af[kt], bfr, acc, 0, 0, 0);
      }
      int ncol = nt * 16 + (lane & 15);
      float badd = w ? 0.f : bb[nt];
      #pragma unroll
      for (int reg = 0; reg < 4; ++reg) {
        int rr = r0 + cg * 4 + reg;
        if (valid && rr < n)
          outp[(size_t)rr * 128 + ncol] = (ushort_t)f2bf(acc[reg] + badd);
      }
    }
    if (w == 0) __syncthreads();
  }
}

// ---------------- hybrid: layer-1 dual GEMM (two-phase) || scatter+aux1
__global__ __launch_bounds__(256)
void k_dual_scatter(const ushort_t* __restrict__ A, const short* __restrict__ Wp,
                    const float* __restrict__ bias1,
                    ushort_t* __restrict__ out1, ushort_t* __restrict__ out2,
                    int n, int ngemm,
                    const int* __restrict__ ei, int E, int nE,
                    int* __restrict__ cursor,
                    int* __restrict__ csr_src, int* __restrict__ csr_dst,
                    int* __restrict__ csr_eid,
                    const float* __restrict__ pos,
                    const float* __restrict__ cw1, const float* __restrict__ cb1,
                    const float* __restrict__ cw2, const float* __restrict__ cb2,
                    float4* __restrict__ aux) {
  __shared__ short BL[128 * 128];        // 32KB
  if ((int)blockIdx.x < ngemm) {
    dual_body(A, Wp, bias1, out1, out2, n, blockIdx.x, BL);
    return;
  }
  // ---- scatter + fused layer-1 aux
  int e = (blockIdx.x - ngemm) * 256 + threadIdx.x;
  if (e >= nE) return;
  int s, d, id;
  if (e < E) { s = ei[e]; d = ei[E + e]; id = e; }
  else       { s = d = e - E; id = -1; }
  int slot = atomicAdd(&cursor[(size_t)d * 32], 1);
  csr_src[slot] = s;
  csr_dst[slot] = d;
  csr_eid[slot] = id;
  float dx = pos[s*3+0] - pos[d*3+0];
  float dy = pos[s*3+1] - pos[d*3+1];
  float dz = pos[s*3+2] - pos[d*3+2];
  float dist = sqrtf(dx*dx + dy*dy + dz*dz + 1e-8f);
  float hh = cb2[0];
  #pragma unroll 4
  for (int j = 0; j < 128; ++j)
    hh += fmaxf(fmaf(dist, cw1[j], cb1[j]), 0.f) * cw2[j];
  float4 o; o.x = dist; o.y = hh * dx; o.z = hh * dy; o.w = hh * dz;
  aux[slot] = o;
}

// standalone two-phase dual (layer 2)
__global__ __launch_bounds__(256)
void k_mgemm_dual2(const ushort_t* __restrict__ A, const short* __restrict__ Wp,
                   const float* __restrict__ bias1,
                   ushort_t* __restrict__ out1, ushort_t* __restrict__ out2, int n) {
  __shared__ short BL[128 * 128];
  dual_body(A, Wp, bias1, out1, out2, n, blockIdx.x, BL);
}

// ---------------- single node GEMM body (32KB)
__device__ __forceinline__
void mgemm_body(const ushort_t* A, const short* Wp, const float* bias,
                const ushort_t* resid, const float* degf, ushort_t* out,
                float* out64, int n, int bid, short* BL) {
  const int NT = 8;
  for (int i = threadIdx.x; i < 2048; i += 256)
    ((int4*)BL)[i] = ((const int4*)Wp)[i];
  __syncthreads();
  int t = threadIdx.x, wid = t >> 6, lane = t & 63;
  int cg = lane >> 4;
  float bb[NT];
  #pragma unroll
  for (int nt = 0; nt < NT; ++nt)
    bb[nt] = bias ? bias[nt * 16 + (lane & 15)] : 0.f;
  int ntiles = (n + 15) >> 4;
  int tile = bid * 4 + wid;
  if (tile >= ntiles) return;
  int r0 = tile << 4;
  int arow = r0 + (lane & 15);
  int crow = arow < n ? arow : 0;
  const ushort_t* Ar = A + (size_t)crow * 128;
  s16x8 Af[4];
  #pragma unroll
  for (int kt = 0; kt < 4; ++kt)
    Af[kt] = *(const s16x8*)(Ar + kt * 32 + cg * 8);
  float dsc[4];
  #pragma unroll
  for (int reg = 0; reg < 4; ++reg) {
    int rr = r0 + cg * 4 + reg;
    dsc[reg] = degf ? degf[rr < n ? rr : 0] : 1.f;
  }
  #pragma unroll
  for (int nt = 0; nt < NT; ++nt) {
    f32x4 acc = {0.f, 0.f, 0.f, 0.f};
    #pragma unroll
    for (int kt = 0; kt < 4; ++kt) {
      s16x8 bfr = *(const s16x8*)&BL[((kt * NT + nt) * 64 + lane) * 8];
      acc = __builtin_amdgcn_mfma_f32_16x16x32_bf16(Af[kt], bfr, acc, 0, 0, 0);
    }
    int ncol = nt * 16 + (lane & 15);
    #pragma unroll
    for (int reg = 0; reg < 4; ++reg) {
      int rr = r0 + cg * 4 + reg;
      if (rr < n) {
        float v = acc[reg] + dsc[reg] * bb[nt];
        if (resid) v += bf2f(resid[(size_t)rr * 128 + ncol]);
        out[(size_t)rr * 128 + ncol] = (ushort_t)f2bf(v);
        if (out64 && ncol < 64) out64[(size_t)rr * 64 + ncol] = v;
      }
    }
  }
}

__global__ __launch_bounds__(256)
void k_mgemm(const ushort_t* __restrict__ A, const short* __restrict__ Wp,
             const float* __restrict__ bias, const ushort_t* __restrict__ resid,
             const float* __restrict__ degf, ushort_t* __restrict__ out,
             float* __restrict__ out64, int n) {
  __shared__ short BL[128 * 128];
  mgemm_body(A, Wp, bias, resid, degf, out, out64, n, blockIdx.x, BL);
}

// hybrid: post-GEMM layer1 || aux2 (dist for layer 2)
__global__ __launch_bounds__(256)
void k_post_aux(const ushort_t* __restrict__ A, const short* __restrict__ Wp,
                const float* __restrict__ bias, const ushort_t* __restrict__ resid,
                const float* __restrict__ degf, ushort_t* __restrict__ out,
                int n, int ngemm,
                const int* __restrict__ csr_src, const int* __restrict__ csr_dst,
                int nE, const float* __restrict__ pos1, float* __restrict__ auxd) {
  __shared__ short BL[128 * 128];
  if ((int)blockIdx.x < ngemm) {
    mgemm_body(A, Wp, bias, resid, degf, out, nullptr, n, blockIdx.x, BL);
    return;
  }
  int k = (blockIdx.x - ngemm) * 256 + threadIdx.x;
  if (k >= nE) return;
  int s = csr_src[k], d = csr_dst[k];
  float dx = pos1[s*3+0] - pos1[d*3+0];
  float dy = pos1[s*3+1] - pos1[d*3+1];
  float dz = pos1[s*3+2] - pos1[d*3+2];
  auxd[k] = sqrtf(dx*dx + dy*dy + dz*dz + 1e-8f);
}

// ---------------- bond-pre dual GEMM (COLS=64, 32KB single-phase)
__global__ __launch_bounds__(256)
void k_mgemm_dual64(const ushort_t* __restrict__ A, const short* __restrict__ Wp,
                    const float* __restrict__ bias1,
                    ushort_t* __restrict__ out1, ushort_t* __restrict__ out2, int n) {
  const int COLS = 64, NT = 4;
  __shared__ short BL[2 * 128 * COLS];
  for (int i = threadIdx.x; i < 2 * 128 * COLS / 8; i += 256)
    ((int4*)BL)[i] = ((const int4*)Wp)[i];
  __syncthreads();
  int t = threadIdx.x, wid = t >> 6, lane = t & 63;
  int cg = lane >> 4;
  float bb[NT];
  #pragma unroll
  for (int nt = 0; nt < NT; ++nt)
    bb[nt] = bias1 ? bias1[nt * 16 + (lane & 15)] : 0.f;
  int ntiles = (n + 15) >> 4;
  for (int tile = blockIdx.x * 4 + wid; tile < ntiles; tile += gridDim.x * 4) {
    int r0 = tile << 4;
    int arow = r0 + (lane & 15);
    int crow = arow < n ? arow : 0;
    const ushort_t* Ar = A + (size_t)crow * 128;
    s16x8 Af[4];
    #pragma unroll
    for (int kt = 0; kt < 4; ++kt)
      Af[kt] = *(const s16x8*)(Ar + kt * 32 + cg * 8);
    #pragma unroll
    for (int w = 0; w < 2; ++w) {
      ushort_t* outp = w ? out2 : out1;
      #pragma unroll
      for (int nt = 0; nt < NT; ++nt) {
        f32x4 acc = {0.f, 0.f, 0.f, 0.f};
        #pragma unroll
        for (int kt = 0; kt < 4; ++kt) {
          s16x8 bfr = *(const s16x8*)&BL[(w * 128 * COLS / 8 + (kt * NT + nt) * 64 + lane) * 8];
          acc = __builtin_amdgcn_mfma_f32_16x16x32_bf16(Af[kt], bfr, acc, 0, 0, 0);
        }
        int ncol = nt * 16 + (lane & 15);
        float badd = w ? 0.f : bb[nt];
        #pragma unroll
        for (int reg = 0; reg < 4; ++reg) {
          int rr = r0 + cg * 4 + reg;
          if (rr < n)
            outp[(size_t)rr * COLS + ncol] = (ushort_t)f2bf(acc[reg] + badd);
        }
      }
    }
  }
}

// ---------------- per-dst aggregation (r12 half-stream pipeline)
template<bool L1>
__global__ __launch_bounds__(256)
void k_aggregate(const int* __restrict__ row, const int* __restrict__ csr_src,
                 const float4* __restrict__ aux4, const float* __restrict__ auxd,
                 const ushort_t* __restrict__ Pb, const ushort_t* __restrict__ Qb,
                 const float* __restrict__ w1r,
                 const float* __restrict__ posin, float* __restrict__ posout,
                 float* __restrict__ degf, ushort_t* __restrict__ Sb, int n) {
  int gw = (blockIdx.x * 256 + threadIdx.x) >> 6;
  if (gw >= n) return;
  int lane = threadIdx.x & 63;
  int half = lane >> 5, sub = lane & 31;
  int r0 = row[gw], r1 = row[gw + 1];
  int r1m1 = r1 - 1;

  ushort4 pu = *(const ushort4*)&Pb[(size_t)gw * 128 + (sub << 2)];
  float p0 = bf2f(pu.x), p1 = bf2f(pu.y), p2 = bf2f(pu.z), p3 = bf2f(pu.w);
  float4 wv = *(const float4*)&w1r[sub << 2];
  float a0 = 0.f, a1 = 0.f, a2 = 0.f, a3 = 0.f, pacc = 0.f;

  int k0 = r0 + half;
  bool any = k0 < r1;
  int kA = k0 < r1m1 ? k0 : r1m1;
  int kB = k0 + 2 < r1m1 ? k0 + 2 : r1m1;
  int sA = csr_src[kA];
  int sB = csr_src[kB];
  ushort4 qA = *(const ushort4*)&Qb[(size_t)sA * 128 + (sub << 2)];
  float4 axA, axB;
  if (L1) axA = aux4[kA]; else { axA.x = auxd[kA]; axA.y = axA.z = axA.w = 0.f; }

  for (int k = k0; k + 2 < r1; k += 2) {
    int kn4 = k + 4 < r1m1 ? k + 4 : r1m1;
    int sC = csr_src[kn4];
    ushort4 qB = *(const ushort4*)&Qb[(size_t)sB * 128 + (sub << 2)];
    if (L1) axB = aux4[k + 2]; else { axB.x = auxd[k + 2]; axB.y = axB.z = axB.w = 0.f; }
    a0 += fmaxf(fmaf(axA.x, wv.x, p0 + bf2f(qA.x)), 0.f);
    a1 += fmaxf(fmaf(axA.x, wv.y, p1 + bf2f(qA.y)), 0.f);
    a2 += fmaxf(fmaf(axA.x, wv.z, p2 + bf2f(qA.z)), 0.f);
    a3 += fmaxf(fmaf(axA.x, wv.w, p3 + bf2f(qA.w)), 0.f);
    if (L1 && sub < 3) pacc += (sub == 0) ? axA.y : (sub == 1) ? axA.z : axA.w;
    qA = qB; axA = axB; sB = sC;
  }
  if (any) {
    a0 += fmaxf(fmaf(axA.x, wv.x, p0 + bf2f(qA.x)), 0.f);
    a1 += fmaxf(fmaf(axA.x, wv.y, p1 + bf2f(qA.y)), 0.f);
    a2 += fmaxf(fmaf(axA.x, wv.z, p2 + bf2f(qA.z)), 0.f);
    a3 += fmaxf(fmaf(axA.x, wv.w, p3 + bf2f(qA.w)), 0.f);
    if (L1 && sub < 3) pacc += (sub == 0) ? axA.y : (sub == 1) ? axA.z : axA.w;
  }

  a0 += __shfl_xor(a0, 32, 64);
  a1 += __shfl_xor(a1, 32, 64);
  a2 += __shfl_xor(a2, 32, 64);
  a3 += __shfl_xor(a3, 32, 64);
  if (L1) pacc += __shfl_xor(pacc, 32, 64);

  if (half == 0) {
    ushort4 o;
    o.x = (ushort_t)f2bf(a0); o.y = (ushort_t)f2bf(a1);
    o.z = (ushort_t)f2bf(a2); o.w = (ushort_t)f2bf(a3);
    *(ushort4*)&Sb[(size_t)gw * 128 + (sub << 2)] = o;
  }
  if (L1) {
    if (lane < 3) posout[gw * 3 + lane] = posin[gw * 3 + lane] + pacc;
    if (lane == 0) degf[gw] = (float)(r1 - r0);
  }
}

// ---------------- bond predictor in CSR(dst) order
__global__ __launch_bounds__(256)
void k_bond(const int* __restrict__ csr_src, const int* __restrict__ csr_dst,
            const int* __restrict__ csr_eid, int nE,
            const ushort_t* __restrict__ U, const ushort_t* __restrict__ V,
            const float* __restrict__ w2, const float* __restrict__ b2,
            float* __restrict__ out) {
  __shared__ float w2L[256];
  w2L[threadIdx.x] = w2[threadIdx.x];
  __syncthreads();
  int k = blockIdx.x * 256 + threadIdx.x;
  if (k >= nE) return;
  int eid = csr_eid[k];
  if (eid < 0) return;
  int s = csr_src[k], d = csr_dst[k];
  const ushort_t* Ur = U + (size_t)s * 64;
  const ushort_t* Vr = V + (size_t)d * 64;
  float l0 = b2[0], l1 = b2[1], l2 = b2[2], l3 = b2[3];
  #pragma unroll
  for (int c8 = 0; c8 < 8; ++c8) {
    u16x8 u = *(const u16x8*)(Ur + c8 * 8);
    u16x8 v = *(const u16x8*)(Vr + c8 * 8);
    #pragma unroll
    for (int j = 0; j < 8; ++j) {
      float h = fmaxf(bf2f(u[j]) + bf2f(v[j]), 0.f);
      const float* wr = &w2L[(c8 * 8 + j) * 4];
      l0 = fmaf(h, wr[0], l0);
      l1 = fmaf(h, wr[1], l1);
      l2 = fmaf(h, wr[2], l2);
      l3 = fmaf(h, wr[3], l3);
    }
  }
  float4 o = {l0, l1, l2, l3};
  *(float4*)&out[(size_t)eid * 4] = o;
}

extern "C" void kernel_launch(void* const* d_in, const int* in_sizes, int n_in,
                              void* d_out, int out_size, void* d_ws, size_t ws_size,
                              hipStream_t stream) {
  const float* x_t   = (const float*)d_in[0];
  const float* pos   = (const float*)d_in[1];
  const int*   ei    = (const int*)d_in[2];
  const int*   tt    = (const int*)d_in[3];
  const float* cond  = (const float*)d_in[4];
  const float* te_w1 = (const float*)d_in[5];
  const float* te_b1 = (const float*)d_in[6];
  const float* te_w2 = (const float*)d_in[7];
  const float* te_b2 = (const float*)d_in[8];
  const float* l1_nm_w1 = (const float*)d_in[9];
  const float* l1_nm_b1 = (const float*)d_in[10];
  const float* l1_nm_w2 = (const float*)d_in[11];
  const float* l1_nm_b2 = (const float*)d_in[12];
  const float* l1_cm_w1 = (const float*)d_in[13];
  const float* l1_cm_b1 = (const float*)d_in[14];
  const float* l1_cm_w2 = (const float*)d_in[15];
  const float* l1_cm_b2 = (const float*)d_in[16];
  const float* l2_nm_w1 = (const float*)d_in[17];
  const float* l2_nm_b1 = (const float*)d_in[18];
  const float* l2_nm_w2 = (const float*)d_in[19];
  const float* l2_nm_b2 = (const float*)d_in[20];
  const float* bp_w1 = (const float*)d_in[25];
  const float* bp_b1 = (const float*)d_in[26];
  const float* bp_w2 = (const float*)d_in[27];
  const float* bp_b2 = (const float*)d_in[28];

  int n  = in_sizes[0] / 64;
  int E_ = in_sizes[2] / 2;
  int nE = E_ + n;
  int nb = (n + 255) / 256;

  uintptr_t base = (uintptr_t)d_ws;
  size_t off = 0;
  auto alloc = [&](size_t bytes) -> void* {
    void* p = (void*)(base + off);
    off += (bytes + 255) & ~(size_t)255;
    return p;
  };
  short* pk    = (short*)alloc(114688 * 2);
  short* pk_l1_t = pk;
  short* pk_l1_2 = pk + 32768;
  short* pk_l2_t = pk + 49152;
  short* pk_l2_2 = pk + 81920;
  short* pk_bp_t = pk + 98304;
  ushort_t* X0b = (ushort_t*)alloc((size_t)n * 128 * 2);
  ushort_t* X1b = (ushort_t*)alloc((size_t)n * 128 * 2);
  ushort_t* Sb  = (ushort_t*)alloc((size_t)n * 128 * 2);
  ushort_t* Pbf = (ushort_t*)alloc((size_t)n * 128 * 2);
  ushort_t* Qbf = (ushort_t*)alloc((size_t)n * 128 * 2);
  int*   deg    = (int*)alloc((size_t)n * 4);
  int*   tmp    = (int*)alloc((size_t)n * 4);
  int*   bsum   = (int*)alloc(256 * 4);
  int*   rowp   = (int*)alloc(((size_t)n + 1) * 4);
  int*   cursor = (int*)alloc((size_t)n * 128);
  int*   csrsrc = (int*)alloc((size_t)nE * 4);
  int*   csrdst = (int*)alloc((size_t)nE * 4);
  int*   csreid = (int*)alloc((size_t)nE * 4);
  float4* aux4  = (float4*)alloc((size_t)nE * 16);
  float* auxd   = (float*)alloc((size_t)nE * 4);
  float* degf   = (float*)alloc((size_t)n * 4);
  float* pos1   = (float*)alloc((size_t)n * 3 * 4);
  ushort_t* Ubf = Pbf;
  ushort_t* Vbf = Qbf;

  int nbBuild = (n * 16 + 255) / 256;
  int ndc = (E_ + 255) / 256;
  int nscat = (nE + 255) / 256;
  int nagg = (n + 3) / 4;
  int ngemm = (((n + 15) >> 4) + 3) / 4;

  hipMemsetAsync(deg, 0, (size_t)n * 4, stream);
  k_front<<<448 + nbBuild + ndc, 256, 0, stream>>>(
      l1_nm_w1, l1_nm_w1 + 16384, l1_nm_w2, l2_nm_w1, l2_nm_w1 + 16384, l2_nm_w2,
      bp_w1, bp_w1 + 128 * 64, pk,
      tt, te_w1, te_b1, te_w2, te_b2,
      x_t, cond, X0b, n, ei + E_, E_, deg, nbBuild);
  k_scan1<<<nb, 256, 0, stream>>>(deg, tmp, bsum, n);
  k_scan2<<<1, 256, 0, stream>>>(bsum, nb);
  k_scan3<<<nb, 256, 0, stream>>>(deg, tmp, bsum, rowp, cursor, n);

  // layer-1 dual GEMM (two-phase 32KB) || scatter+aux1
  k_dual_scatter<<<ngemm + nscat, 256, 0, stream>>>(
      X0b, pk_l1_t, l1_nm_b1, Pbf, Qbf, n, ngemm,
      ei, E_, nE, cursor, csrsrc, csrdst, csreid,
      pos, l1_cm_w1, l1_cm_b1, l1_cm_w2, l1_cm_b2, aux4);

  k_aggregate<true><<<nagg, 256, 0, stream>>>(rowp, csrsrc, aux4, nullptr, Pbf, Qbf,
      l1_nm_w1 + 256 * 128, pos, pos1, degf, Sb, n);

  // post-GEMM layer1 || aux2
  k_post_aux<<<ngemm + nscat, 256, 0, stream>>>(
      Sb, pk_l1_2, l1_nm_b2, X0b, degf, X1b, n, ngemm,
      csrsrc, csrdst, nE, pos1, auxd);

  // layer 2
  k_mgemm_dual2<<<ngemm, 256, 0, stream>>>(X1b, pk_l2_t, l2_nm_b1, Pbf, Qbf, n);
  k_aggregate<false><<<nagg, 256, 0, stream>>>(rowp, csrsrc, nullptr, auxd, Pbf, Qbf,
      l2_nm_w1 + 256 * 128, nullptr, nullptr, nullptr, Sb, n);
  k_mgemm<<<ngemm, 256, 0, stream>>>(Sb, pk_l2_2, l2_nm_b2, X1b, degf, X0b, (float*)d_out, n);

  // bond predictor
  k_mgemm_dual64<<<ngemm, 256, 0, stream>>>(X0b, pk_bp_t, bp_b1, Ubf, Vbf, n);
  k_bond<<<nscat, 256, 0, stream>>>(csrsrc, csrdst, csreid, nE, Ubf, Vbf,
                                    bp_w2, bp_b2, (float*)d_out + (size_t)n * 64);
}

// Round 16
// 283.070 us; speedup vs baseline: 1.4589x; 1.0360x over previous
//
#include <hip/hip_runtime.h>
#include <hip/hip_bf16.h>
#include <stdint.h>

typedef float  f32x4 __attribute__((ext_vector_type(4)));
typedef short  s16x8 __attribute__((ext_vector_type(8)));
typedef unsigned short u16x8 __attribute__((ext_vector_type(8)));
typedef unsigned short ushort_t;

__device__ __forceinline__ short f2bf(float f) {
  union { float f; unsigned u; } x; x.f = f;
  unsigned r = x.u + 0x7fffu + ((x.u >> 16) & 1u);
  return (short)(r >> 16);
}
__device__ __forceinline__ float bf2f(unsigned short u) {
  union { unsigned u; float f; } x; x.u = ((unsigned)u) << 16; return x.f;
}
__device__ __forceinline__ float i2f(int v) {
  union { int i; float f; } x; x.i = v; return x.f;
}
__device__ __forceinline__ int f2i(float v) {
  union { float f; int i; } x; x.f = v; return x.i;
}

__device__ __forceinline__ void pack_one(const float* W, int cols, int local, short* dst) {
  int NT = cols / 16;
  int j = local & 7, l = (local >> 3) & 63;
  int nt = (local >> 9) % NT;
  int kt = (local >> 9) / NT;
  int k = kt * 32 + ((l >> 4) * 8) + j;
  int ncol = nt * 16 + (l & 15);
  dst[local] = f2bf(W[(size_t)k * cols + ncol]);
}

// ---------------- front: weight pack + build_xin (temb in-block) + deg_count
__global__ __launch_bounds__(256)
void k_front(const float* __restrict__ w0, const float* __restrict__ w1,
             const float* __restrict__ w2, const float* __restrict__ w3,
             const float* __restrict__ w4, const float* __restrict__ w5,
             const float* __restrict__ w6, const float* __restrict__ w7,
             short* __restrict__ out,
             const int* __restrict__ t, const float* __restrict__ tw1,
             const float* __restrict__ tb1, const float* __restrict__ tw2,
             const float* __restrict__ tb2,
             const float* __restrict__ xt, const float* __restrict__ cond,
             ushort_t* __restrict__ X, int n,
             const int* __restrict__ edst, int E, int* __restrict__ deg,
             int nbBuild) {
  int b = blockIdx.x;
  if (b < 448) {
    int i = b * 256 + threadIdx.x;
    if (i < 98304) {
      int r = i >> 14, local = i & 16383;
      const float* W = r == 0 ? w0 : r == 1 ? w1 : r == 2 ? w2 : r == 3 ? w3 : r == 4 ? w4 : w5;
      pack_one(W, 128, local, out + r * 16384);
    } else {
      int j = i - 98304;
      int r = j >> 13, local = j & 8191;
      pack_one(r ? w7 : w6, 64, local, out + 98304 + r * 8192);
    }
    return;
  }
  b -= 448;
  if (b < nbBuild) {
    __shared__ float h[32], tembL[32];
    int j = threadIdx.x;
    if (j < 32) h[j] = fmaxf(((float)t[0] / 1000.0f) * tw1[j] + tb1[j], 0.f);
    __syncthreads();
    if (j < 32) {
      float acc = tb2[j];
      for (int k2 = 0; k2 < 32; ++k2) acc += h[k2] * tw2[k2 * 32 + j];
      tembL[j] = acc;
    }
    __syncthreads();
    int i = b * 256 + threadIdx.x;
    if (i >= n * 16) return;
    int node = i >> 4, c8 = i & 15;
    float va[8];
    if (c8 < 8)       { const float* p = &xt[(size_t)node * 64 + c8 * 8];
                        #pragma unroll
                        for (int q = 0; q < 8; ++q) va[q] = p[q]; }
    else if (c8 < 12) { const float* p = &cond[(c8 - 8) * 8];
                        #pragma unroll
                        for (int q = 0; q < 8; ++q) va[q] = p[q]; }
    else              { const float* p = &tembL[(c8 - 12) * 8];
                        #pragma unroll
                        for (int q = 0; q < 8; ++q) va[q] = p[q]; }
    u16x8 o;
    #pragma unroll
    for (int q = 0; q < 8; ++q) o[q] = f2bf(va[q]);
    *(u16x8*)&X[(size_t)node * 128 + c8 * 8] = o;
    return;
  }
  b -= nbBuild;
  int e = b * 256 + threadIdx.x;
  if (e < E) atomicAdd(&deg[edst[e]], 1);
}

// ---------------- scans (self-loop +1 folded in)
__global__ void k_scan1(const int* __restrict__ deg, int* __restrict__ tmp,
                        int* __restrict__ bsum, int n) {
  __shared__ int sh[256];
  int i = blockIdx.x * 256 + threadIdx.x;
  int v = (i < n) ? deg[i] + 1 : 0;
  sh[threadIdx.x] = v; __syncthreads();
  for (int off = 1; off < 256; off <<= 1) {
    int t = (threadIdx.x >= off) ? sh[threadIdx.x - off] : 0;
    __syncthreads();
    sh[threadIdx.x] += t;
    __syncthreads();
  }
  if (i < n) tmp[i] = sh[threadIdx.x];
  if (threadIdx.x == 255) bsum[blockIdx.x] = sh[255];
}
__global__ void k_scan2(int* __restrict__ bsum, int nb) {
  __shared__ int sh[256];
  int t = threadIdx.x;
  int v = (t < nb) ? bsum[t] : 0;
  sh[t] = v; __syncthreads();
  for (int off = 1; off < 256; off <<= 1) {
    int u = (t >= off) ? sh[t - off] : 0;
    __syncthreads();
    sh[t] += u;
    __syncthreads();
  }
  if (t < nb) bsum[t] = sh[t] - v;
}
__global__ void k_scan3(const int* __restrict__ deg, const int* __restrict__ tmp,
                        const int* __restrict__ bsum, int* __restrict__ row,
                        int* __restrict__ cursor, int n) {
  int i = blockIdx.x * 256 + threadIdx.x;
  if (i < n) {
    int incl = tmp[i] + bsum[i >> 8];
    row[i + 1] = incl;
    cursor[(size_t)i * 32] = incl - (deg[i] + 1);
    if (i == 0) row[0] = 0;
  }
}

// dual-GEMM body, two-phase 32KB staging (A frags persist in regs)
__device__ __forceinline__
void dual_body(const ushort_t* A, const short* Wp, const float* bias1,
               ushort_t* out1, ushort_t* out2, int n, int bid, short* BL) {
  const int NT = 8;
  int t = threadIdx.x, wid = t >> 6, lane = t & 63;
  int cg = lane >> 4;
  int ntiles = (n + 15) >> 4;
  int tile = bid * 4 + wid;
  bool valid = tile < ntiles;
  int r0 = (valid ? tile : 0) << 4;
  int arow = r0 + (lane & 15);
  int crow = arow < n ? arow : 0;
  const ushort_t* Ar = A + (size_t)crow * 128;
  s16x8 Af[4];
  #pragma unroll
  for (int kt = 0; kt < 4; ++kt)
    Af[kt] = *(const s16x8*)(Ar + kt * 32 + cg * 8);
  float bb[NT];
  #pragma unroll
  for (int nt = 0; nt < NT; ++nt)
    bb[nt] = bias1 ? bias1[nt * 16 + (lane & 15)] : 0.f;
  #pragma unroll
  for (int w = 0; w < 2; ++w) {
    for (int i = threadIdx.x; i < 2048; i += 256)
      ((int4*)BL)[i] = ((const int4*)Wp)[w * 2048 + i];
    __syncthreads();
    ushort_t* outp = w ? out2 : out1;
    #pragma unroll
    for (int nt = 0; nt < NT; ++nt) {
      f32x4 acc = {0.f, 0.f, 0.f, 0.f};
      #pragma unroll
      for (int kt = 0; kt < 4; ++kt) {
        s16x8 bfr = *(const s16x8*)&BL[((kt * NT + nt) * 64 + lane) * 8];
        acc = __builtin_amdgcn_mfma_f32_16x16x32_bf16(Af[kt], bfr, acc, 0, 0, 0);
      }
      int ncol = nt * 16 + (lane & 15);
      float badd = w ? 0.f : bb[nt];
      #pragma unroll
      for (int reg = 0; reg < 4; ++reg) {
        int rr = r0 + cg * 4 + reg;
        if (valid && rr < n)
          outp[(size_t)rr * 128 + ncol] = (ushort_t)f2bf(acc[reg] + badd);
      }
    }
    if (w == 0) __syncthreads();
  }
}

// ---------------- hybrid: layer-1 dual GEMM (two-phase) || scatter -> combined 32B struct
// csr32[slot] = int4{s, d, eid, bits(dist)} , int4{bits(hx), bits(hy), bits(hz), 0}
__global__ __launch_bounds__(256)
void k_dual_scatter(const ushort_t* __restrict__ A, const short* __restrict__ Wp,
                    const float* __restrict__ bias1,
                    ushort_t* __restrict__ out1, ushort_t* __restrict__ out2,
                    int n, int ngemm,
                    const int* __restrict__ ei, int E, int nE,
                    int* __restrict__ cursor, int4* __restrict__ csr32,
                    const float* __restrict__ pos,
                    const float* __restrict__ cw1, const float* __restrict__ cb1,
                    const float* __restrict__ cw2, const float* __restrict__ cb2) {
  __shared__ short BL[128 * 128];        // 32KB
  if ((int)blockIdx.x < ngemm) {
    dual_body(A, Wp, bias1, out1, out2, n, blockIdx.x, BL);
    return;
  }
  int e = (blockIdx.x - ngemm) * 256 + threadIdx.x;
  if (e >= nE) return;
  int s, d, id;
  if (e < E) { s = ei[e]; d = ei[E + e]; id = e; }
  else       { s = d = e - E; id = -1; }
  int slot = atomicAdd(&cursor[(size_t)d * 32], 1);
  float dx = pos[s*3+0] - pos[d*3+0];
  float dy = pos[s*3+1] - pos[d*3+1];
  float dz = pos[s*3+2] - pos[d*3+2];
  float dist = sqrtf(dx*dx + dy*dy + dz*dz + 1e-8f);
  float hh = cb2[0];
  #pragma unroll 4
  for (int j = 0; j < 128; ++j)
    hh += fmaxf(fmaf(dist, cw1[j], cb1[j]), 0.f) * cw2[j];
  int4 c0; c0.x = s; c0.y = d; c0.z = id; c0.w = f2i(dist);
  int4 c1; c1.x = f2i(hh * dx); c1.y = f2i(hh * dy); c1.z = f2i(hh * dz); c1.w = 0;
  csr32[(size_t)slot * 2 + 0] = c0;
  csr32[(size_t)slot * 2 + 1] = c1;
}

// standalone two-phase dual (layer 2)
__global__ __launch_bounds__(256)
void k_mgemm_dual2(const ushort_t* __restrict__ A, const short* __restrict__ Wp,
                   const float* __restrict__ bias1,
                   ushort_t* __restrict__ out1, ushort_t* __restrict__ out2, int n) {
  __shared__ short BL[128 * 128];
  dual_body(A, Wp, bias1, out1, out2, n, blockIdx.x, BL);
}

// ---------------- single node GEMM body (32KB)
__device__ __forceinline__
void mgemm_body(const ushort_t* A, const short* Wp, const float* bias,
                const ushort_t* resid, const float* degf, ushort_t* out,
                float* out64, int n, int bid, short* BL) {
  const int NT = 8;
  for (int i = threadIdx.x; i < 2048; i += 256)
    ((int4*)BL)[i] = ((const int4*)Wp)[i];
  __syncthreads();
  int t = threadIdx.x, wid = t >> 6, lane = t & 63;
  int cg = lane >> 4;
  float bb[NT];
  #pragma unroll
  for (int nt = 0; nt < NT; ++nt)
    bb[nt] = bias ? bias[nt * 16 + (lane & 15)] : 0.f;
  int ntiles = (n + 15) >> 4;
  int tile = bid * 4 + wid;
  if (tile >= ntiles) return;
  int r0 = tile << 4;
  int arow = r0 + (lane & 15);
  int crow = arow < n ? arow : 0;
  const ushort_t* Ar = A + (size_t)crow * 128;
  s16x8 Af[4];
  #pragma unroll
  for (int kt = 0; kt < 4; ++kt)
    Af[kt] = *(const s16x8*)(Ar + kt * 32 + cg * 8);
  float dsc[4];
  #pragma unroll
  for (int reg = 0; reg < 4; ++reg) {
    int rr = r0 + cg * 4 + reg;
    dsc[reg] = degf ? degf[rr < n ? rr : 0] : 1.f;
  }
  #pragma unroll
  for (int nt = 0; nt < NT; ++nt) {
    f32x4 acc = {0.f, 0.f, 0.f, 0.f};
    #pragma unroll
    for (int kt = 0; kt < 4; ++kt) {
      s16x8 bfr = *(const s16x8*)&BL[((kt * NT + nt) * 64 + lane) * 8];
      acc = __builtin_amdgcn_mfma_f32_16x16x32_bf16(Af[kt], bfr, acc, 0, 0, 0);
    }
    int ncol = nt * 16 + (lane & 15);
    #pragma unroll
    for (int reg = 0; reg < 4; ++reg) {
      int rr = r0 + cg * 4 + reg;
      if (rr < n) {
        float v = acc[reg] + dsc[reg] * bb[nt];
        if (resid) v += bf2f(resid[(size_t)rr * 128 + ncol]);
        out[(size_t)rr * 128 + ncol] = (ushort_t)f2bf(v);
        if (out64 && ncol < 64) out64[(size_t)rr * 64 + ncol] = v;
      }
    }
  }
}

__global__ __launch_bounds__(256)
void k_mgemm(const ushort_t* __restrict__ A, const short* __restrict__ Wp,
             const float* __restrict__ bias, const ushort_t* __restrict__ resid,
             const float* __restrict__ degf, ushort_t* __restrict__ out,
             float* __restrict__ out64, int n) {
  __shared__ short BL[128 * 128];
  mgemm_body(A, Wp, bias, resid, degf, out, out64, n, blockIdx.x, BL);
}

// hybrid: post-GEMM layer1 || aux2 (dist for layer 2, reads csr32)
__global__ __launch_bounds__(256)
void k_post_aux(const ushort_t* __restrict__ A, const short* __restrict__ Wp,
                const float* __restrict__ bias, const ushort_t* __restrict__ resid,
                const float* __restrict__ degf, ushort_t* __restrict__ out,
                int n, int ngemm,
                const int4* __restrict__ csr32,
                int nE, const float* __restrict__ pos1, float* __restrict__ auxd) {
  __shared__ short BL[128 * 128];
  if ((int)blockIdx.x < ngemm) {
    mgemm_body(A, Wp, bias, resid, degf, out, nullptr, n, blockIdx.x, BL);
    return;
  }
  int k = (blockIdx.x - ngemm) * 256 + threadIdx.x;
  if (k >= nE) return;
  int4 c = csr32[(size_t)k * 2];
  int s = c.x, d = c.y;
  float dx = pos1[s*3+0] - pos1[d*3+0];
  float dy = pos1[s*3+1] - pos1[d*3+1];
  float dz = pos1[s*3+2] - pos1[d*3+2];
  auxd[k] = sqrtf(dx*dx + dy*dy + dz*dz + 1e-8f);
}

// ---------------- bond-pre dual GEMM (COLS=64, 32KB single-phase)
__global__ __launch_bounds__(256)
void k_mgemm_dual64(const ushort_t* __restrict__ A, const short* __restrict__ Wp,
                    const float* __restrict__ bias1,
                    ushort_t* __restrict__ out1, ushort_t* __restrict__ out2, int n) {
  const int COLS = 64, NT = 4;
  __shared__ short BL[2 * 128 * COLS];
  for (int i = threadIdx.x; i < 2 * 128 * COLS / 8; i += 256)
    ((int4*)BL)[i] = ((const int4*)Wp)[i];
  __syncthreads();
  int t = threadIdx.x, wid = t >> 6, lane = t & 63;
  int cg = lane >> 4;
  float bb[NT];
  #pragma unroll
  for (int nt = 0; nt < NT; ++nt)
    bb[nt] = bias1 ? bias1[nt * 16 + (lane & 15)] : 0.f;
  int ntiles = (n + 15) >> 4;
  for (int tile = blockIdx.x * 4 + wid; tile < ntiles; tile += gridDim.x * 4) {
    int r0 = tile << 4;
    int arow = r0 + (lane & 15);
    int crow = arow < n ? arow : 0;
    const ushort_t* Ar = A + (size_t)crow * 128;
    s16x8 Af[4];
    #pragma unroll
    for (int kt = 0; kt < 4; ++kt)
      Af[kt] = *(const s16x8*)(Ar + kt * 32 + cg * 8);
    #pragma unroll
    for (int w = 0; w < 2; ++w) {
      ushort_t* outp = w ? out2 : out1;
      #pragma unroll
      for (int nt = 0; nt < NT; ++nt) {
        f32x4 acc = {0.f, 0.f, 0.f, 0.f};
        #pragma unroll
        for (int kt = 0; kt < 4; ++kt) {
          s16x8 bfr = *(const s16x8*)&BL[(w * 128 * COLS / 8 + (kt * NT + nt) * 64 + lane) * 8];
          acc = __builtin_amdgcn_mfma_f32_16x16x32_bf16(Af[kt], bfr, acc, 0, 0, 0);
        }
        int ncol = nt * 16 + (lane & 15);
        float badd = w ? 0.f : bb[nt];
        #pragma unroll
        for (int reg = 0; reg < 4; ++reg) {
          int rr = r0 + cg * 4 + reg;
          if (rr < n)
            outp[(size_t)rr * COLS + ncol] = (ushort_t)f2bf(acc[reg] + badd);
        }
      }
    }
  }
}

// ---------------- per-dst aggregation (half-stream pipeline, csr32 reads)
template<bool L1>
__global__ __launch_bounds__(256)
void k_aggregate(const int* __restrict__ row, const int4* __restrict__ csr32,
                 const float* __restrict__ auxd,
                 const ushort_t* __restrict__ Pb, const ushort_t* __restrict__ Qb,
                 const float* __restrict__ w1r,
                 const float* __restrict__ posin, float* __restrict__ posout,
                 float* __restrict__ degf, ushort_t* __restrict__ Sb, int n) {
  int gw = (blockIdx.x * 256 + threadIdx.x) >> 6;
  if (gw >= n) return;
  int lane = threadIdx.x & 63;
  int half = lane >> 5, sub = lane & 31;
  int r0 = row[gw], r1 = row[gw + 1];
  int r1m1 = r1 - 1;

  ushort4 pu = *(const ushort4*)&Pb[(size_t)gw * 128 + (sub << 2)];
  float p0 = bf2f(pu.x), p1 = bf2f(pu.y), p2 = bf2f(pu.z), p3 = bf2f(pu.w);
  float4 wv = *(const float4*)&w1r[sub << 2];
  float a0 = 0.f, a1 = 0.f, a2 = 0.f, a3 = 0.f, pacc = 0.f;

  int k0 = r0 + half;
  bool any = k0 < r1;
  int kA = k0 < r1m1 ? k0 : r1m1;
  int kB = k0 + 2 < r1m1 ? k0 + 2 : r1m1;
  int4 cA = csr32[(size_t)kA * 2];
  int sB = csr32[(size_t)kB * 2].x;
  ushort4 qA = *(const ushort4*)&Qb[(size_t)cA.x * 128 + (sub << 2)];
  float dA, dB;
  float4 hA, hB;
  if (L1) { hA = *(const float4*)&csr32[(size_t)kA * 2 + 1]; dA = i2f(cA.w); }
  else    { dA = auxd[kA]; }

  for (int k = k0; k + 2 < r1; k += 2) {
    int kn4 = k + 4 < r1m1 ? k + 4 : r1m1;
    int kc2 = k + 2;
    int4 cB; cB.x = sB;
    int sC = csr32[(size_t)kn4 * 2].x;
    ushort4 qB = *(const ushort4*)&Qb[(size_t)sB * 128 + (sub << 2)];
    if (L1) {
      int4 cB2 = csr32[(size_t)kc2 * 2];
      hB = *(const float4*)&csr32[(size_t)kc2 * 2 + 1];
      dB = i2f(cB2.w);
    } else {
      dB = auxd[kc2];
    }
    a0 += fmaxf(fmaf(dA, wv.x, p0 + bf2f(qA.x)), 0.f);
    a1 += fmaxf(fmaf(dA, wv.y, p1 + bf2f(qA.y)), 0.f);
    a2 += fmaxf(fmaf(dA, wv.z, p2 + bf2f(qA.z)), 0.f);
    a3 += fmaxf(fmaf(dA, wv.w, p3 + bf2f(qA.w)), 0.f);
    if (L1 && sub < 3) pacc += (sub == 0) ? hA.x : (sub == 1) ? hA.y : hA.z;
    qA = qB; dA = dB; hA = hB; sB = sC;
  }
  if (any) {
    a0 += fmaxf(fmaf(dA, wv.x, p0 + bf2f(qA.x)), 0.f);
    a1 += fmaxf(fmaf(dA, wv.y, p1 + bf2f(qA.y)), 0.f);
    a2 += fmaxf(fmaf(dA, wv.z, p2 + bf2f(qA.z)), 0.f);
    a3 += fmaxf(fmaf(dA, wv.w, p3 + bf2f(qA.w)), 0.f);
    if (L1 && sub < 3) pacc += (sub == 0) ? hA.x : (sub == 1) ? hA.y : hA.z;
  }

  a0 += __shfl_xor(a0, 32, 64);
  a1 += __shfl_xor(a1, 32, 64);
  a2 += __shfl_xor(a2, 32, 64);
  a3 += __shfl_xor(a3, 32, 64);
  if (L1) pacc += __shfl_xor(pacc, 32, 64);

  if (half == 0) {
    ushort4 o;
    o.x = (ushort_t)f2bf(a0); o.y = (ushort_t)f2bf(a1);
    o.z = (ushort_t)f2bf(a2); o.w = (ushort_t)f2bf(a3);
    *(ushort4*)&Sb[(size_t)gw * 128 + (sub << 2)] = o;
  }
  if (L1) {
    if (lane < 3) posout[gw * 3 + lane] = posin[gw * 3 + lane] + pacc;
    if (lane == 0) degf[gw] = (float)(r1 - r0);
  }
}

// ---------------- bond predictor in CSR(dst) order (csr32 reads)
__global__ __launch_bounds__(256)
void k_bond(const int4* __restrict__ csr32, int nE,
            const ushort_t* __restrict__ U, const ushort_t* __restrict__ V,
            const float* __restrict__ w2, const float* __restrict__ b2,
            float* __restrict__ out) {
  __shared__ float w2L[256];
  w2L[threadIdx.x] = w2[threadIdx.x];
  __syncthreads();
  int k = blockIdx.x * 256 + threadIdx.x;
  if (k >= nE) return;
  int4 c = csr32[(size_t)k * 2];
  int eid = c.z;
  if (eid < 0) return;
  int s = c.x, d = c.y;
  const ushort_t* Ur = U + (size_t)s * 64;
  const ushort_t* Vr = V + (size_t)d * 64;
  float l0 = b2[0], l1 = b2[1], l2 = b2[2], l3 = b2[3];
  #pragma unroll
  for (int c8 = 0; c8 < 8; ++c8) {
    u16x8 u = *(const u16x8*)(Ur + c8 * 8);
    u16x8 v = *(const u16x8*)(Vr + c8 * 8);
    #pragma unroll
    for (int j = 0; j < 8; ++j) {
      float h = fmaxf(bf2f(u[j]) + bf2f(v[j]), 0.f);
      const float* wr = &w2L[(c8 * 8 + j) * 4];
      l0 = fmaf(h, wr[0], l0);
      l1 = fmaf(h, wr[1], l1);
      l2 = fmaf(h, wr[2], l2);
      l3 = fmaf(h, wr[3], l3);
    }
  }
  float4 o = {l0, l1, l2, l3};
  *(float4*)&out[(size_t)eid * 4] = o;
}

extern "C" void kernel_launch(void* const* d_in, const int* in_sizes, int n_in,
                              void* d_out, int out_size, void* d_ws, size_t ws_size,
                              hipStream_t stream) {
  const float* x_t   = (const float*)d_in[0];
  const float* pos   = (const float*)d_in[1];
  const int*   ei    = (const int*)d_in[2];
  const int*   tt    = (const int*)d_in[3];
  const float* cond  = (const float*)d_in[4];
  const float* te_w1 = (const float*)d_in[5];
  const float* te_b1 = (const float*)d_in[6];
  const float* te_w2 = (const float*)d_in[7];
  const float* te_b2 = (const float*)d_in[8];
  const float* l1_nm_w1 = (const float*)d_in[9];
  const float* l1_nm_b1 = (const float*)d_in[10];
  const float* l1_nm_w2 = (const float*)d_in[11];
  const float* l1_nm_b2 = (const float*)d_in[12];
  const float* l1_cm_w1 = (const float*)d_in[13];
  const float* l1_cm_b1 = (const float*)d_in[14];
  const float* l1_cm_w2 = (const float*)d_in[15];
  const float* l1_cm_b2 = (const float*)d_in[16];
  const float* l2_nm_w1 = (const float*)d_in[17];
  const float* l2_nm_b1 = (const float*)d_in[18];
  const float* l2_nm_w2 = (const float*)d_in[19];
  const float* l2_nm_b2 = (const float*)d_in[20];
  const float* bp_w1 = (const float*)d_in[25];
  const float* bp_b1 = (const float*)d_in[26];
  const float* bp_w2 = (const float*)d_in[27];
  const float* bp_b2 = (const float*)d_in[28];

  int n  = in_sizes[0] / 64;
  int E_ = in_sizes[2] / 2;
  int nE = E_ + n;
  int nb = (n + 255) / 256;

  uintptr_t base = (uintptr_t)d_ws;
  size_t off = 0;
  auto alloc = [&](size_t bytes) -> void* {
    void* p = (void*)(base + off);
    off += (bytes + 255) & ~(size_t)255;
    return p;
  };
  short* pk    = (short*)alloc(114688 * 2);
  short* pk_l1_t = pk;
  short* pk_l1_2 = pk + 32768;
  short* pk_l2_t = pk + 49152;
  short* pk_l2_2 = pk + 81920;
  short* pk_bp_t = pk + 98304;
  ushort_t* X0b = (ushort_t*)alloc((size_t)n * 128 * 2);
  ushort_t* X1b = (ushort_t*)alloc((size_t)n * 128 * 2);
  ushort_t* Sb  = (ushort_t*)alloc((size_t)n * 128 * 2);
  ushort_t* Pbf = (ushort_t*)alloc((size_t)n * 128 * 2);
  ushort_t* Qbf = (ushort_t*)alloc((size_t)n * 128 * 2);
  int*   deg    = (int*)alloc((size_t)n * 4);
  int*   tmp    = (int*)alloc((size_t)n * 4);
  int*   bsum   = (int*)alloc(256 * 4);
  int*   rowp   = (int*)alloc(((size_t)n + 1) * 4);
  int*   cursor = (int*)alloc((size_t)n * 128);
  int4*  csr32  = (int4*)alloc((size_t)nE * 32);
  float* auxd   = (float*)alloc((size_t)nE * 4);
  float* degf   = (float*)alloc((size_t)n * 4);
  float* pos1   = (float*)alloc((size_t)n * 3 * 4);
  ushort_t* Ubf = Pbf;
  ushort_t* Vbf = Qbf;

  int nbBuild = (n * 16 + 255) / 256;
  int ndc = (E_ + 255) / 256;
  int nscat = (nE + 255) / 256;
  int nagg = (n + 3) / 4;
  int ngemm = (((n + 15) >> 4) + 3) / 4;

  hipMemsetAsync(deg, 0, (size_t)n * 4, stream);
  k_front<<<448 + nbBuild + ndc, 256, 0, stream>>>(
      l1_nm_w1, l1_nm_w1 + 16384, l1_nm_w2, l2_nm_w1, l2_nm_w1 + 16384, l2_nm_w2,
      bp_w1, bp_w1 + 128 * 64, pk,
      tt, te_w1, te_b1, te_w2, te_b2,
      x_t, cond, X0b, n, ei + E_, E_, deg, nbBuild);
  k_scan1<<<nb, 256, 0, stream>>>(deg, tmp, bsum, n);
  k_scan2<<<1, 256, 0, stream>>>(bsum, nb);
  k_scan3<<<nb, 256, 0, stream>>>(deg, tmp, bsum, rowp, cursor, n);

  // layer-1 dual GEMM (two-phase 32KB) || scatter (combined 32B struct)
  k_dual_scatter<<<ngemm + nscat, 256, 0, stream>>>(
      X0b, pk_l1_t, l1_nm_b1, Pbf, Qbf, n, ngemm,
      ei, E_, nE, cursor, csr32,
      pos, l1_cm_w1, l1_cm_b1, l1_cm_w2, l1_cm_b2);

  k_aggregate<true><<<nagg, 256, 0, stream>>>(rowp, csr32, nullptr, Pbf, Qbf,
      l1_nm_w1 + 256 * 128, pos, pos1, degf, Sb, n);

  // post-GEMM layer1 || aux2
  k_post_aux<<<ngemm + nscat, 256, 0, stream>>>(
      Sb, pk_l1_2, l1_nm_b2, X0b, degf, X1b, n, ngemm,
      csr32, nE, pos1, auxd);

  // layer 2
  k_mgemm_dual2<<<ngemm, 256, 0, stream>>>(X1b, pk_l2_t, l2_nm_b1, Pbf, Qbf, n);
  k_aggregate<false><<<nagg, 256, 0, stream>>>(rowp, csr32, auxd, Pbf, Qbf,
      l2_nm_w1 + 256 * 128, nullptr, nullptr, nullptr, Sb, n);
  k_mgemm<<<ngemm, 256, 0, stream>>>(Sb, pk_l2_2, l2_nm_b2, X1b, degf, X0b, (float*)d_out, n);

  // bond predictor
  k_mgemm_dual64<<<ngemm, 256, 0, stream>>>(X0b, pk_bp_t, bp_b1, Ubf, Vbf, n);
  k_bond<<<nscat, 256, 0, stream>>>(csr32, nE, Ubf, Vbf,
                                    bp_w2, bp_b2, (float*)d_out + (size_t)n * 64);
}